// Round 2
// baseline (1016.222 us; speedup 1.0000x reference)
//
#include <hip/hip_runtime.h>
#include <math.h>

// ---------- types / helpers ----------
typedef __attribute__((ext_vector_type(8))) short s16x8;
typedef __attribute__((ext_vector_type(4))) float f32x4;

__device__ __forceinline__ float bf2f(unsigned short u) {
    union { unsigned int i; float f; } c; c.i = ((unsigned int)u) << 16; return c.f;
}
__device__ __forceinline__ unsigned short f2bf(float f) {
    union { float f; unsigned int i; } c; c.f = f;
    unsigned int r = c.i + 0x7fffu + ((c.i >> 16) & 1u);
    return (unsigned short)(r >> 16);
}
__device__ __forceinline__ float wave_sum(float v) {
#pragma unroll
    for (int o = 32; o; o >>= 1) v += __shfl_xor(v, o, 64);
    return v;
}
__device__ __forceinline__ float wave_max(float v) {
#pragma unroll
    for (int o = 32; o; o >>= 1) v = fmaxf(v, __shfl_xor(v, o, 64));
    return v;
}
__device__ __forceinline__ void async_load16(const void* g, void* l) {
    __builtin_amdgcn_global_load_lds(
        (const __attribute__((address_space(1))) unsigned int*)g,
        (__attribute__((address_space(3))) unsigned int*)l, 16, 0, 0);
}

// ---------- 256x256 deep-pipelined bf16 GEMM: C[M,N] = A[M,K] * BT[N,K]^T ----------
// 512 thr = 8 waves (2M x 4N); K-slice = 32; LDS = ring of 4 K-slices per matrix.
// LDS layout per slice = MFMA fragment order: 16 subtiles (16 rows x 32 k) of 1KB,
// lane-linear -> ds_read_b128 at base+lane*16 (conflict-free) and global_load_lds
// lane-linear dest matches (permutation carried by per-lane global source addr).
// Counted vmcnt(6) steady state (never 0 in main loop); tail 6/4/0.
enum { EP_BF16 = 0, EP_ADDF32 = 1, EP_BIAS_ELU_BF16 = 2, EP_QKV = 4, EP_BIAS_ADDBF16 = 5 };

template <int EP>
__global__ __launch_bounds__(512, 2) void gemm256(
    const unsigned short* __restrict__ A, int lda,
    const unsigned short* __restrict__ BT, int ldb,
    int K, int ldc,
    float* Cf, unsigned short* Cb,
    const float* __restrict__ bias, const float* addsrc,
    const unsigned short* __restrict__ addb,
    unsigned short* vtout)
{
    __shared__ __align__(16) unsigned short sA[4 * 8192];  // 4 slots x 16KB
    __shared__ __align__(16) unsigned short sB[4 * 8192];
    const int tid = threadIdx.x;
    const int w = tid >> 6, l = tid & 63;
    const int wr = w >> 2, wc = w & 3;          // wave grid 2M x 4N
    const int lm = l & 15, lq = l >> 4;

    // XCD-chunked bijective swizzle (nwg % 8 == 0 for all our grids)
    unsigned int i = blockIdx.y * gridDim.x + blockIdx.x;
    const unsigned int chunk = (gridDim.x * gridDim.y) >> 3;
    i = (i & 7u) * chunk + (i >> 3);
    const int tileX = i % gridDim.x, tileY = i / gridDim.x;
    const int rowBase = tileY * 256, colBase = tileX * 256;

    f32x4 acc[8][4] = {};

    // staging source pointers: lane -> (row = subtile*16 + lm, k = lq*8 ..)
    const unsigned short* gAr0 = A + (size_t)(rowBase + w * 16 + lm) * lda + lq * 8;
    const unsigned short* gAr1 = A + (size_t)(rowBase + (8 + w) * 16 + lm) * lda + lq * 8;
    const unsigned short* gBr0 = BT + (size_t)(colBase + w * 16 + lm) * ldb + lq * 8;
    const unsigned short* gBr1 = BT + (size_t)(colBase + (8 + w) * 16 + lm) * ldb + lq * 8;

#define STAGE_A(J) do { const int _sl = ((J) & 3) * 8192; \
    async_load16(gAr0 + (size_t)(J) * 32, sA + _sl + w * 512); \
    async_load16(gAr1 + (size_t)(J) * 32, sA + _sl + (8 + w) * 512); } while (0)
#define STAGE_B(J) do { const int _sl = ((J) & 3) * 8192; \
    async_load16(gBr0 + (size_t)(J) * 32, sB + _sl + w * 512); \
    async_load16(gBr1 + (size_t)(J) * 32, sB + _sl + (8 + w) * 512); } while (0)

#define KSTEP(S) do { \
    const int _slot = (S) & 3; \
    const unsigned short* pa = sA + _slot * 8192 + wr * 4096 + l * 8; \
    const unsigned short* pb = sB + _slot * 8192 + wc * 2048 + l * 8; \
    s16x8 af[4], bfr[4]; \
    _Pragma("unroll") for (int n = 0; n < 4; ++n) bfr[n] = *(const s16x8*)(pb + n * 512); \
    _Pragma("unroll") for (int m = 0; m < 4; ++m) af[m] = *(const s16x8*)(pa + m * 512); \
    __builtin_amdgcn_s_setprio(1); \
    _Pragma("unroll") for (int m = 0; m < 4; ++m) \
    _Pragma("unroll") for (int n = 0; n < 4; ++n) \
        acc[m][n] = __builtin_amdgcn_mfma_f32_16x16x32_bf16(af[m], bfr[n], acc[m][n], 0, 0, 0); \
    __builtin_amdgcn_s_setprio(0); \
    _Pragma("unroll") for (int m = 0; m < 4; ++m) af[m] = *(const s16x8*)(pa + (4 + m) * 512); \
    __builtin_amdgcn_s_setprio(1); \
    _Pragma("unroll") for (int m = 0; m < 4; ++m) \
    _Pragma("unroll") for (int n = 0; n < 4; ++n) \
        acc[4 + m][n] = __builtin_amdgcn_mfma_f32_16x16x32_bf16(af[m], bfr[n], acc[4 + m][n], 0, 0, 0); \
    __builtin_amdgcn_s_setprio(0); \
} while (0)

    const int NK = K >> 5;  // K-slices of 32; NK >= 32 here
    // prologue: units A0,B0,A1,B1,A2 (10 loads/thread)
    STAGE_A(0); STAGE_B(0); STAGE_A(1); STAGE_B(1); STAGE_A(2);

    for (int s = 0; s < NK - 3; ++s) {
        asm volatile("s_waitcnt vmcnt(6)" ::: "memory");
        __builtin_amdgcn_s_barrier();
        __builtin_amdgcn_sched_barrier(0);
        STAGE_B(s + 2); STAGE_A(s + 3);
        KSTEP(s);
    }
    // tail: ksteps NK-3, NK-2, NK-1
    asm volatile("s_waitcnt vmcnt(6)" ::: "memory");
    __builtin_amdgcn_s_barrier();
    __builtin_amdgcn_sched_barrier(0);
    STAGE_B(NK - 1);
    KSTEP(NK - 3);
    asm volatile("s_waitcnt vmcnt(4)" ::: "memory");
    __builtin_amdgcn_s_barrier();
    __builtin_amdgcn_sched_barrier(0);
    KSTEP(NK - 2);
    asm volatile("s_waitcnt vmcnt(0)" ::: "memory");
    __builtin_amdgcn_s_barrier();
    __builtin_amdgcn_sched_barrier(0);
    KSTEP(NK - 1);

#undef STAGE_A
#undef STAGE_B
#undef KSTEP

    if (EP == EP_QKV && colBase >= 2048) {
        // V part transposed: vT[(b*16+h)*64+d][n]
#pragma unroll
        for (int mi = 0; mi < 8; ++mi) {
            const int row0 = rowBase + wr * 128 + mi * 16 + lq * 4;
            const int bb = row0 >> 12, nn = row0 & 4095;
#pragma unroll
            for (int ni = 0; ni < 4; ++ni) {
                const int c = colBase + wc * 64 + ni * 16 + lm - 2048;
                const int hv = c >> 6, dv = c & 63;
                ushort4 u;
                u.x = f2bf(acc[mi][ni][0]); u.y = f2bf(acc[mi][ni][1]);
                u.z = f2bf(acc[mi][ni][2]); u.w = f2bf(acc[mi][ni][3]);
                *(ushort4*)(vtout + ((size_t)(bb * 16 + hv) * 64 + dv) * 4096 + nn) = u;
            }
        }
    } else {
#pragma unroll
        for (int mi = 0; mi < 8; ++mi) {
            const int r0 = rowBase + wr * 128 + mi * 16 + lq * 4;
#pragma unroll
            for (int ni = 0; ni < 4; ++ni) {
                const int c = colBase + wc * 64 + ni * 16 + lm;
                float bv = 0.f;
                if (EP == EP_BIAS_ELU_BF16 || EP == EP_BIAS_ADDBF16) bv = bias[c];
#pragma unroll
                for (int r = 0; r < 4; ++r) {
                    const size_t idx = (size_t)(r0 + r) * ldc + c;
                    float v = acc[mi][ni][r] + bv;
                    if (EP == EP_ADDF32) v += addsrc[idx];
                    if (EP == EP_BIAS_ADDBF16) v += bf2f(addb[idx]);
                    if (EP == EP_BIAS_ELU_BF16) v = v > 0.f ? v : (expf(v) - 1.f);
                    if (EP == EP_BF16 || EP == EP_BIAS_ELU_BF16 || EP == EP_QKV) Cb[idx] = f2bf(v);
                    else Cf[idx] = v;
                }
            }
        }
    }
}

// ---------- all weight transposes + f32->bf16 in one dispatch ----------
__global__ __launch_bounds__(256) void transpose_all(
    const float* __restrict__ Wq, const float* __restrict__ Wk,
    const float* __restrict__ Wv, const float* __restrict__ Wo,
    const float* __restrict__ W1, const float* __restrict__ W2,
    unsigned short* WqkvT, unsigned short* WoT,
    unsigned short* W1T, unsigned short* W2T)
{
    __shared__ float t[32][33];
    const int bid = blockIdx.x;
    const float* in;
    unsigned short* out;
    int R, C, tx32, ty32;
    if (bid < 4096) {
        const int job = bid >> 10, tile = bid & 1023;
        ty32 = tile >> 5; tx32 = tile & 31;
        R = 1024; C = 1024;
        if (job == 0)      { in = Wq; out = WqkvT; }
        else if (job == 1) { in = Wk; out = WqkvT + 1024 * 1024; }
        else if (job == 2) { in = Wv; out = WqkvT + 2 * 1024 * 1024; }
        else               { in = Wo; out = WoT; }
    } else if (bid < 8192) {
        const int tile = bid - 4096;           // W1 [1024,4096]: 128 x-tiles, 32 y-tiles
        tx32 = tile & 127; ty32 = tile >> 7;
        R = 1024; C = 4096; in = W1; out = W1T;
    } else {
        const int tile = bid - 8192;           // W2 [4096,1024]: 32 x-tiles, 128 y-tiles
        tx32 = tile & 31; ty32 = tile >> 5;
        R = 4096; C = 1024; in = W2; out = W2T;
    }
    const int c0 = tx32 * 32, r0 = ty32 * 32;
    const int tx = threadIdx.x, ty = threadIdx.y;
#pragma unroll
    for (int j = 0; j < 4; ++j)
        t[ty + j * 8][tx] = in[(size_t)(r0 + ty + j * 8) * C + c0 + tx];
    __syncthreads();
#pragma unroll
    for (int j = 0; j < 4; ++j) {
        int cc = ty + j * 8;
        out[(size_t)(c0 + cc) * R + r0 + tx] = f2bf(t[tx][cc]);
    }
}

__global__ __launch_bounds__(256) void cvt_bf16(const float4* in, ushort4* out) {
    size_t i = (size_t)blockIdx.x * 256 + threadIdx.x;
    float4 v = in[i];
    ushort4 o; o.x = f2bf(v.x); o.y = f2bf(v.y); o.z = f2bf(v.z); o.w = f2bf(v.w);
    out[i] = o;
}

// ---------- FAVOR+ features via MFMA ----------
__global__ __launch_bounds__(256, 2) void feat_mfma(
    const unsigned short* __restrict__ qkvb, const float* __restrict__ proj,
    unsigned short* __restrict__ qf, float* __restrict__ kdash,
    float* __restrict__ diagk, float* __restrict__ bmax)
{
    __shared__ __align__(16) unsigned short sQ[8192];  // [2 ks][128 rows][32 k]
    __shared__ __align__(16) unsigned short sK[8192];
    __shared__ __align__(16) unsigned short sP[4096];  // proj [2 ks][64 m][32 k]
    __shared__ float sdq[128], sdk[128];
    __shared__ float swm[4];
    const int tid = threadIdx.x, w = tid >> 6, l = tid & 63;
    const int t0 = blockIdx.x * 8;
    const int lm = l & 15, lq = l >> 4;

#pragma unroll
    for (int j = 0; j < 4; ++j) {
        const int lt = 2 * w + (j & 1), ks = j >> 1;
        const size_t g = (size_t)(t0 + lt) * 3072 + (l >> 2) * 64 + ks * 32 + (l & 3) * 8;
        async_load16(qkvb + g, sQ + ks * 4096 + lt * 512);
        async_load16(qkvb + g + 1024, sK + ks * 4096 + lt * 512);
    }
    for (int i = tid; i < 4096; i += 256) {
        int m = i >> 6, d = i & 63;
        sP[(d >> 5) * 2048 + m * 32 + (d & 31)] = f2bf(proj[i]);
    }
    __syncthreads();

    {
        int r = tid & 127;
        const unsigned short* src = (tid < 128) ? sQ : sK;
        float s = 0.f;
#pragma unroll
        for (int ks = 0; ks < 2; ++ks) {
            const s16x8* p = (const s16x8*)(src + ks * 4096 + r * 32);
#pragma unroll
            for (int c = 0; c < 4; ++c) {
                s16x8 v = p[c];
#pragma unroll
                for (int e = 0; e < 8; ++e) { float f = bf2f((unsigned short)v[e]); s += f * f; }
            }
        }
        if (tid < 128) sdq[r] = s * 0.0625f; else sdk[r] = s * 0.0625f;
    }
    __syncthreads();

    s16x8 pf2[2][4];
#pragma unroll
    for (int ks = 0; ks < 2; ++ks)
#pragma unroll
        for (int ni = 0; ni < 4; ++ni)
            pf2[ks][ni] = *(const s16x8*)(sP + ks * 2048 + (ni * 16 + lm) * 32 + lq * 8);
    f32x4 qa[2][4] = {}, ka[2][4] = {};
#pragma unroll
    for (int i = 0; i < 2; ++i) {
        const int rowt = (w * 2 + i) * 16 + lm;
#pragma unroll
        for (int ks = 0; ks < 2; ++ks) {
            s16x8 aq = *(const s16x8*)(sQ + ks * 4096 + rowt * 32 + lq * 8);
            s16x8 ak = *(const s16x8*)(sK + ks * 4096 + rowt * 32 + lq * 8);
#pragma unroll
            for (int ni = 0; ni < 4; ++ni) {
                qa[i][ni] = __builtin_amdgcn_mfma_f32_16x16x32_bf16(aq, pf2[ks][ni], qa[i][ni], 0, 0, 0);
                ka[i][ni] = __builtin_amdgcn_mfma_f32_16x16x32_bf16(ak, pf2[ks][ni], ka[i][ni], 0, 0, 0);
            }
        }
    }

    const float dn = 0.35355339059327373f;
    float kmax = -3.0e38f;
#pragma unroll
    for (int i = 0; i < 2; ++i) {
#pragma unroll
        for (int r = 0; r < 4; ++r) {
            const int row = (w * 2 + i) * 16 + lq * 4 + r;
            float q0 = qa[i][0][r] * dn, q1 = qa[i][1][r] * dn;
            float q2 = qa[i][2][r] * dn, q3 = qa[i][3][r] * dn;
            float mq = fmaxf(fmaxf(q0, q1), fmaxf(q2, q3));
#pragma unroll
            for (int o = 1; o < 16; o <<= 1) mq = fmaxf(mq, __shfl_xor(mq, o, 64));
            const float dg = sdq[row];
            const size_t ob = (size_t)t0 * 1024 + (size_t)row * 64 + lm;
            qf[ob]      = f2bf(0.125f * (expf(q0 - dg - mq) + 1e-6f));
            qf[ob + 16] = f2bf(0.125f * (expf(q1 - dg - mq) + 1e-6f));
            qf[ob + 32] = f2bf(0.125f * (expf(q2 - dg - mq) + 1e-6f));
            qf[ob + 48] = f2bf(0.125f * (expf(q3 - dg - mq) + 1e-6f));
#pragma unroll
            for (int ni = 0; ni < 4; ++ni) {
                float kd = ka[i][ni][r] * dn;
                kdash[ob + ni * 16] = kd;
                kmax = fmaxf(kmax, kd);
            }
        }
    }
    kmax = wave_max(kmax);
    if (l == 0) swm[w] = kmax;
    __syncthreads();
    if (tid < 128) diagk[t0 * 16 + tid] = sdk[tid];
    if (tid == 0) bmax[blockIdx.x] = fmaxf(fmaxf(swm[0], swm[1]), fmaxf(swm[2], swm[3]));
}

__global__ __launch_bounds__(256) void max_reduce(const float* bm, float* mx) {
    const int tid = threadIdx.x;
    float m = -3.0e38f;
    for (int i = tid; i < 2048; i += 256) m = fmaxf(m, bm[i]);
    m = wave_max(m);
    __shared__ float s[4];
    if ((tid & 63) == 0) s[tid >> 6] = m;
    __syncthreads();
    if (tid == 0) mx[0] = fmaxf(fmaxf(s[0], s[1]), fmaxf(s[2], s[3]));
}

// ---------- fused kf + kv/ksum via MFMA ----------
__global__ __launch_bounds__(256, 2) void kv_fused(
    const float* __restrict__ kdash, const float* __restrict__ diagk,
    const float* __restrict__ mx, const unsigned short* __restrict__ vT,
    float* kv, float* ksum)
{
    __shared__ __align__(16) unsigned short sKF[64 * 72];
    __shared__ __align__(16) unsigned short sV[64 * 72];
    __shared__ float sDiag[1024];
    const int tid = threadIdx.x, w = tid >> 6, l = tid & 63;
    const int bh = blockIdx.x, b = bh >> 4, h = bh & 15;
    const int n0 = blockIdx.y * 1024;
    const int lm = l & 15, lq = l >> 4;
    const float mxv = mx[0];

    for (int i = tid; i < 1024; i += 256)
        sDiag[i] = diagk[(size_t)(b * 4096 + n0 + i) * 16 + h] + mxv;

    s16x8 onesf;
    {
        short ov = (lm == 0) ? (short)0x3F80 : (short)0;
#pragma unroll
        for (int j = 0; j < 8; ++j) onesf[j] = ov;
    }
    f32x4 acc[4] = {};
    f32x4 accS = {};
    __syncthreads();

    for (int c0 = 0; c0 < 1024; c0 += 64) {
        __syncthreads();
        {
            const int n = c0 + l;
            const size_t krow = ((size_t)(b * 4096 + n0 + n)) * 1024 + h * 64 + w * 16;
            const float4* kp = (const float4*)(kdash + krow);
            float4 k0 = kp[0], k1 = kp[1], k2 = kp[2], k3 = kp[3];
            const float dg = sDiag[n];
            float vv[16] = {k0.x, k0.y, k0.z, k0.w, k1.x, k1.y, k1.z, k1.w,
                            k2.x, k2.y, k2.z, k2.w, k3.x, k3.y, k3.z, k3.w};
            unsigned short* dst = sKF + (w * 16) * 72 + l;
#pragma unroll
            for (int e = 0; e < 16; ++e)
                dst[e * 72] = f2bf(0.125f * (expf(vv[e] - dg) + 1e-6f));
        }
        {
            const int d = tid >> 2, nq = tid & 3;
            const uint4* vp = (const uint4*)(vT + ((size_t)bh * 64 + d) * 4096 + n0 + c0 + nq * 16);
            uint4 v0 = vp[0], v1 = vp[1];
            uint4* ldst = (uint4*)(sV + d * 72 + nq * 16);
            ldst[0] = v0; ldst[1] = v1;
        }
        __syncthreads();
#pragma unroll
        for (int ks = 0; ks < 2; ++ks) {
            s16x8 a = *(const s16x8*)(sKF + (w * 16 + lm) * 72 + ks * 32 + lq * 8);
            accS = __builtin_amdgcn_mfma_f32_16x16x32_bf16(a, onesf, accS, 0, 0, 0);
#pragma unroll
            for (int ni = 0; ni < 4; ++ni) {
                s16x8 bf = *(const s16x8*)(sV + (ni * 16 + lm) * 72 + ks * 32 + lq * 8);
                acc[ni] = __builtin_amdgcn_mfma_f32_16x16x32_bf16(a, bf, acc[ni], 0, 0, 0);
            }
        }
    }

    const size_t kvbase = (size_t)bh * 4096;
#pragma unroll
    for (int ni = 0; ni < 4; ++ni)
#pragma unroll
        for (int r = 0; r < 4; ++r)
            atomicAdd(kv + kvbase + (size_t)(w * 16 + lq * 4 + r) * 64 + ni * 16 + lm, acc[ni][r]);
    if (lm == 0)
#pragma unroll
        for (int r = 0; r < 4; ++r)
            atomicAdd(ksum + bh * 64 + w * 16 + lq * 4 + r, accS[r]);
}

// ---------- attention combine via MFMA, den folded as output column 64 ----------
__global__ __launch_bounds__(256, 2) void attn_mfma(const unsigned short* __restrict__ qf,
                                                    const float* __restrict__ kv,
                                                    const float* __restrict__ ksum,
                                                    unsigned short* __restrict__ attn) {
    __shared__ __align__(16) unsigned short sA[8192];  // [2 ks][128 rows][32 m]
    __shared__ __align__(16) unsigned short sB[5120];  // [2 ks][80 cols][32 m]; col64=ksum
    const int tid = threadIdx.x, w = tid >> 6, l = tid & 63;
    const int bh = blockIdx.x, b = bh >> 4, h = bh & 15;
    const int n0 = blockIdx.y * 128;
    const int lm = l & 15, lq = l >> 4;

#pragma unroll
    for (int j = 0; j < 4; ++j) {
        const int r0 = w * 32 + (j & 1) * 16, ks = j >> 1;
        const size_t g = (size_t)(b * 4096 + n0 + r0 + (l >> 2)) * 1024 + h * 64 + ks * 32 + (l & 3) * 8;
        async_load16(qf + g, sA + ks * 4096 + r0 * 32);
    }
    for (int i = tid; i < 5120; i += 256) sB[i] = 0;
    __syncthreads();
    for (int i = tid; i < 4096; i += 256) {
        int m = i >> 6, d = i & 63;
        sB[(m >> 5) * 2560 + d * 32 + (m & 31)] = f2bf(kv[(size_t)bh * 4096 + i]);
    }
    if (tid < 64) {
        int m = tid;
        sB[(m >> 5) * 2560 + 64 * 32 + (m & 31)] = f2bf(ksum[bh * 64 + m]);
    }
    __syncthreads();

    s16x8 bf2r[2][5];
#pragma unroll
    for (int ks = 0; ks < 2; ++ks)
#pragma unroll
        for (int ni = 0; ni < 5; ++ni)
            bf2r[ks][ni] = *(const s16x8*)(sB + ks * 2560 + (ni * 16 + lm) * 32 + lq * 8);
    f32x4 acc[2][5] = {};
#pragma unroll
    for (int i = 0; i < 2; ++i) {
        const int rowt = (w * 2 + i) * 16 + lm;
#pragma unroll
        for (int ks = 0; ks < 2; ++ks) {
            s16x8 a = *(const s16x8*)(sA + ks * 4096 + rowt * 32 + lq * 8);
#pragma unroll
            for (int ni = 0; ni < 5; ++ni)
                acc[i][ni] = __builtin_amdgcn_mfma_f32_16x16x32_bf16(a, bf2r[ks][ni], acc[i][ni], 0, 0, 0);
        }
    }
#pragma unroll
    for (int i = 0; i < 2; ++i) {
#pragma unroll
        for (int r = 0; r < 4; ++r) {
            const int row = (w * 2 + i) * 16 + lq * 4 + r;
            float den = __shfl(acc[i][4][r], l & 48, 64);
            float rd = 1.f / den;
            const size_t ob = (size_t)(b * 4096 + n0 + row) * 1024 + h * 64 + lm;
            attn[ob]      = f2bf(acc[i][0][r] * rd);
            attn[ob + 16] = f2bf(acc[i][1][r] * rd);
            attn[ob + 32] = f2bf(acc[i][2][r] * rd);
            attn[ob + 48] = f2bf(acc[i][3][r] * rd);
        }
    }
}

// ---------- LayerNorm (D=1024) ----------
__device__ __forceinline__ float block_sum256(float v, float* sbuf, int tid) {
    v = wave_sum(v);
    __syncthreads();
    if ((tid & 63) == 0) sbuf[tid >> 6] = v;
    __syncthreads();
    return sbuf[0] + sbuf[1] + sbuf[2] + sbuf[3];
}

template <int WF32, int WBF16>
__global__ __launch_bounds__(256) void ln_kernel(const float* src, const float* g, const float* b,
                                                 float* dstf, unsigned short* dstb) {
    __shared__ float sbuf[4];
    const int t = blockIdx.x, tid = threadIdx.x;
    float4 v = ((const float4*)(src + (size_t)t * 1024))[tid];
    float mu = block_sum256(v.x + v.y + v.z + v.w, sbuf, tid) * (1.f / 1024.f);
    float dx = v.x - mu, dy = v.y - mu, dz = v.z - mu, dw = v.w - mu;
    float var = block_sum256(dx * dx + dy * dy + dz * dz + dw * dw, sbuf, tid) * (1.f / 1024.f);
    float r = rsqrtf(var + 1e-6f);
    float4 gv = ((const float4*)g)[tid];
    float4 bv = ((const float4*)b)[tid];
    float4 o;
    o.x = dx * r * gv.x + bv.x; o.y = dy * r * gv.y + bv.y;
    o.z = dz * r * gv.z + bv.z; o.w = dw * r * gv.w + bv.w;
    if (WF32) ((float4*)(dstf + (size_t)t * 1024))[tid] = o;
    if (WBF16) {
        ushort4 u; u.x = f2bf(o.x); u.y = f2bf(o.y); u.z = f2bf(o.z); u.w = f2bf(o.w);
        ((ushort4*)(dstb + (size_t)t * 1024))[tid] = u;
    }
}

// ---------- launcher ----------
extern "C" void kernel_launch(void* const* d_in, const int* in_sizes, int n_in,
                              void* d_out, int out_size, void* d_ws, size_t ws_size,
                              hipStream_t stream) {
    (void)in_sizes; (void)n_in; (void)out_size; (void)ws_size;
    const float* x    = (const float*)d_in[0];
    const float* Wq   = (const float*)d_in[1];
    const float* Wk   = (const float*)d_in[2];
    const float* Wv   = (const float*)d_in[3];
    const float* Wo   = (const float*)d_in[4];
    const float* proj = (const float*)d_in[5];
    const float* W1   = (const float*)d_in[6];
    const float* b1   = (const float*)d_in[7];
    const float* W2   = (const float*)d_in[8];
    const float* b2   = (const float*)d_in[9];
    const float* g1   = (const float*)d_in[10];
    const float* lb1  = (const float*)d_in[11];
    const float* g2   = (const float*)d_in[12];
    const float* lb2  = (const float*)d_in[13];

    char* ws = (char*)d_ws;
    size_t off = 0;
    auto alloc = [&](size_t bytes) { char* p = ws + off; off += (bytes + 255) & ~(size_t)255; return p; };
    unsigned short* WqkvT = (unsigned short*)alloc((size_t)3072 * 1024 * 2);
    unsigned short* WoT   = (unsigned short*)alloc((size_t)1024 * 1024 * 2);
    unsigned short* W1T   = (unsigned short*)alloc((size_t)4096 * 1024 * 2);
    unsigned short* W2T   = (unsigned short*)alloc((size_t)1024 * 4096 * 2);
    unsigned short* xb    = (unsigned short*)alloc((size_t)16384 * 1024 * 2);  // later: attn
    unsigned short* qkvb  = (unsigned short*)alloc((size_t)16384 * 3072 * 2);  // later: out1b + h(lo)
    unsigned short* qf    = (unsigned short*)alloc((size_t)16384 * 1024 * 2);  // later: h(mid)
    unsigned short* vT    = (unsigned short*)alloc((size_t)16384 * 1024 * 2);  // later: h(hi)
    float* kv    = (float*)alloc((size_t)64 * 64 * 64 * 4);
    float* ksum  = (float*)alloc((size_t)64 * 64 * 4);
    float* diagk = (float*)alloc((size_t)16384 * 16 * 4);
    float* bmax  = (float*)alloc((size_t)16384 * 4);
    float* mx    = (float*)alloc(256);

    unsigned short* attnb = xb;
    unsigned short* out1b = qkvb;                                   // 32 MB
    unsigned short* h     = qkvb + (size_t)16384 * 1024;            // 128 MB (qkvb hi + qf + vT)
    float* kdash = (float*)d_out;               // d_out doubles as fp32 scratch
    float* preLN = (float*)d_out;

    transpose_all<<<12288, dim3(32, 8), 0, stream>>>(Wq, Wk, Wv, Wo, W1, W2,
                                                     WqkvT, WoT, W1T, W2T);
    cvt_bf16<<<16384, 256, 0, stream>>>((const float4*)x, (ushort4*)xb);

    // QKV: [16384,1024] x [1024,3072]; Q,K -> qkvb (bf16), V -> vT (transposed)
    gemm256<EP_QKV><<<dim3(12, 64), 512, 0, stream>>>(xb, 1024, WqkvT, 1024, 1024, 3072,
                                                      nullptr, qkvb, nullptr, nullptr, nullptr, vT);
    feat_mfma<<<2048, 256, 0, stream>>>(qkvb, proj, qf, kdash, diagk, bmax);
    max_reduce<<<1, 256, 0, stream>>>(bmax, mx);
    hipMemsetAsync(kv, 0, (size_t)64 * 64 * 64 * 4 + (size_t)64 * 64 * 4, stream);
    kv_fused<<<dim3(64, 4), 256, 0, stream>>>(kdash, diagk, mx, vT, kv, ksum);
    attn_mfma<<<dim3(64, 32), 256, 0, stream>>>(qf, kv, ksum, attnb);
    // attn @ Wo + x -> preLN1 (in d_out)
    gemm256<EP_ADDF32><<<dim3(4, 64), 512, 0, stream>>>(attnb, 1024, WoT, 1024, 1024, 1024,
                                                        preLN, nullptr, nullptr, x, nullptr, nullptr);
    ln_kernel<0, 1><<<16384, 256, 0, stream>>>(preLN, g1, lb1, nullptr, out1b);
    // FFN full-DFF: h = elu(out1b @ W1 + b1)  [16384,4096]
    gemm256<EP_BIAS_ELU_BF16><<<dim3(16, 64), 512, 0, stream>>>(out1b, 1024, W1T, 1024, 1024, 4096,
                                                                nullptr, h, b1, nullptr, nullptr, nullptr);
    // preLN2 = h @ W2 + b2 + out1  (K=4096)
    gemm256<EP_BIAS_ADDBF16><<<dim3(4, 64), 512, 0, stream>>>(h, 4096, W2T, 4096, 4096, 1024,
                                                              preLN, nullptr, b2, nullptr, out1b, nullptr);
    ln_kernel<1, 0><<<16384, 256, 0, stream>>>(preLN, g2, lb2, (float*)d_out, nullptr);
}

// Round 3
// 864.124 us; speedup vs baseline: 1.1760x; 1.1760x over previous
//
#include <hip/hip_runtime.h>
#include <math.h>

// ---------- types / helpers ----------
typedef __attribute__((ext_vector_type(8))) short s16x8;
typedef __attribute__((ext_vector_type(4))) float f32x4;

__device__ __forceinline__ float bf2f(unsigned short u) {
    union { unsigned int i; float f; } c; c.i = ((unsigned int)u) << 16; return c.f;
}
__device__ __forceinline__ unsigned short f2bf(float f) {
    union { float f; unsigned int i; } c; c.f = f;
    unsigned int r = c.i + 0x7fffu + ((c.i >> 16) & 1u);
    return (unsigned short)(r >> 16);
}
__device__ __forceinline__ float wave_sum(float v) {
#pragma unroll
    for (int o = 32; o; o >>= 1) v += __shfl_xor(v, o, 64);
    return v;
}
__device__ __forceinline__ float wave_max(float v) {
#pragma unroll
    for (int o = 32; o; o >>= 1) v = fmaxf(v, __shfl_xor(v, o, 64));
    return v;
}
__device__ __forceinline__ void async_load16(const void* g, void* l) {
    __builtin_amdgcn_global_load_lds(
        (const __attribute__((address_space(1))) unsigned int*)g,
        (__attribute__((address_space(3))) unsigned int*)l, 16, 0, 0);
}

// ---------- 256x256 phase-pipelined bf16 GEMM: C[M,N] = A[M,K] * BT[N,K]^T ----------
// 512 thr = 8 waves (2M x 4N); K-slice = 32; 4-slot LDS ring per matrix (16KB slots).
// LDS layout = MFMA fragment order: 1KB lane-linear subtiles (16 rows x 32 k);
// ds_read_b128 at base+lane*16 -> 0 bank conflicts (measured r2); global_load_lds
// lane-linear dest matches (per-lane global source carries the permutation).
// Each slice = 2 phases: {ds_read 8|4; stage 1 unit; [vmcnt once/slice]; barrier;
// setprio(1); 16 MFMA; setprio(0); barrier}. Counted vmcnt(6) steady; tail 6/4/0.
// NO sched_barrier(0) (m141: order-pinning -40%).
enum { EP_BF16 = 0, EP_ADDF32 = 1, EP_BIAS_ELU_BF16 = 2, EP_QKV = 4, EP_BIAS_ADDBF16 = 5 };

template <int EP>
__global__ __launch_bounds__(512, 2) void gemm256(
    const unsigned short* __restrict__ A, int lda,
    const unsigned short* __restrict__ BT, int ldb,
    int K, int ldc,
    float* Cf, unsigned short* Cb,
    const float* __restrict__ bias, const float* addsrc,
    const unsigned short* __restrict__ addb,
    unsigned short* vtout)
{
    __shared__ __align__(16) unsigned short sA[4 * 8192];  // 4 slots x 16KB
    __shared__ __align__(16) unsigned short sB[4 * 8192];
    const int tid = threadIdx.x;
    const int w = tid >> 6, l = tid & 63;
    const int wr = w >> 2, wc = w & 3;          // wave grid 2M x 4N
    const int lm = l & 15, lq = l >> 4;

    // XCD-chunked bijective swizzle (nwg % 8 == 0 for all our grids)
    unsigned int i = blockIdx.y * gridDim.x + blockIdx.x;
    const unsigned int chunk = (gridDim.x * gridDim.y) >> 3;
    i = (i & 7u) * chunk + (i >> 3);
    const int tileX = i % gridDim.x, tileY = i / gridDim.x;
    const int rowBase = tileY * 256, colBase = tileX * 256;

    f32x4 acc[8][4] = {};

    // staging source: lane -> (row = subtile*16 + lm, k = lq*8)
    const unsigned short* gAr0 = A + (size_t)(rowBase + w * 16 + lm) * lda + lq * 8;
    const unsigned short* gAr1 = A + (size_t)(rowBase + (8 + w) * 16 + lm) * lda + lq * 8;
    const unsigned short* gBr0 = BT + (size_t)(colBase + w * 16 + lm) * ldb + lq * 8;
    const unsigned short* gBr1 = BT + (size_t)(colBase + (8 + w) * 16 + lm) * ldb + lq * 8;

#define STAGE_A(J) do { const int _sl = ((J) & 3) * 8192; \
    async_load16(gAr0 + (size_t)(J) * 32, sA + _sl + w * 512); \
    async_load16(gAr1 + (size_t)(J) * 32, sA + _sl + (8 + w) * 512); } while (0)
#define STAGE_B(J) do { const int _sl = ((J) & 3) * 8192; \
    async_load16(gBr0 + (size_t)(J) * 32, sB + _sl + w * 512); \
    async_load16(gBr1 + (size_t)(J) * 32, sB + _sl + (8 + w) * 512); } while (0)

// One K-slice: 2 phases in the m201 rhythm. DO_B/DO_A/VM are compile-time-foldable
// uniform flags. Residency of slot S was established by the previous slice's
// vmcnt+barrier; this slice's vmcnt+barrier guards the NEXT slice's reads.
#define SLICE(S, DO_B, DO_A, VM) do { \
    const int _slot = (S) & 3; \
    const unsigned short* pa = sA + _slot * 8192 + wr * 4096 + l * 8; \
    const unsigned short* pb = sB + _slot * 8192 + wc * 2048 + l * 8; \
    s16x8 af[4], bfr[4]; \
    _Pragma("unroll") for (int n = 0; n < 4; ++n) bfr[n] = *(const s16x8*)(pb + n * 512); \
    _Pragma("unroll") for (int m = 0; m < 4; ++m) af[m] = *(const s16x8*)(pa + m * 512); \
    if (DO_B) STAGE_B((S) + 2); \
    __builtin_amdgcn_s_barrier(); \
    __builtin_amdgcn_s_setprio(1); \
    _Pragma("unroll") for (int m = 0; m < 4; ++m) \
    _Pragma("unroll") for (int n = 0; n < 4; ++n) \
        acc[m][n] = __builtin_amdgcn_mfma_f32_16x16x32_bf16(af[m], bfr[n], acc[m][n], 0, 0, 0); \
    __builtin_amdgcn_s_setprio(0); \
    __builtin_amdgcn_s_barrier(); \
    _Pragma("unroll") for (int m = 0; m < 4; ++m) af[m] = *(const s16x8*)(pa + (4 + m) * 512); \
    if (DO_A) STAGE_A((S) + 3); \
    if ((VM) == 6) asm volatile("s_waitcnt vmcnt(6)" ::: "memory"); \
    else if ((VM) == 4) asm volatile("s_waitcnt vmcnt(4)" ::: "memory"); \
    else if ((VM) == 0) asm volatile("s_waitcnt vmcnt(0)" ::: "memory"); \
    __builtin_amdgcn_s_barrier(); \
    __builtin_amdgcn_s_setprio(1); \
    _Pragma("unroll") for (int m = 0; m < 4; ++m) \
    _Pragma("unroll") for (int n = 0; n < 4; ++n) \
        acc[4 + m][n] = __builtin_amdgcn_mfma_f32_16x16x32_bf16(af[m], bfr[n], acc[4 + m][n], 0, 0, 0); \
    __builtin_amdgcn_s_setprio(0); \
    __builtin_amdgcn_s_barrier(); \
} while (0)

    const int NK = K >> 5;  // K-slices of 32; NK in {32,128}
    // prologue units: A0,B0,A1,B1,A2 (10 loads/thread); slot0 resident after wait
    STAGE_A(0); STAGE_B(0); STAGE_A(1); STAGE_B(1); STAGE_A(2);
    asm volatile("s_waitcnt vmcnt(6)" ::: "memory");
    __builtin_amdgcn_s_barrier();

    for (int s = 0; s <= NK - 4; ++s) SLICE(s, 1, 1, 6);
    SLICE(NK - 3, 1, 0, 4);
    SLICE(NK - 2, 0, 0, 0);
    SLICE(NK - 1, 0, 0, -1);

#undef STAGE_A
#undef STAGE_B
#undef SLICE

    if (EP == EP_QKV && colBase >= 2048) {
        // V part transposed: vT[(b*16+h)*64+d][n]
#pragma unroll
        for (int mi = 0; mi < 8; ++mi) {
            const int row0 = rowBase + wr * 128 + mi * 16 + lq * 4;
            const int bb = row0 >> 12, nn = row0 & 4095;
#pragma unroll
            for (int ni = 0; ni < 4; ++ni) {
                const int c = colBase + wc * 64 + ni * 16 + lm - 2048;
                const int hv = c >> 6, dv = c & 63;
                ushort4 u;
                u.x = f2bf(acc[mi][ni][0]); u.y = f2bf(acc[mi][ni][1]);
                u.z = f2bf(acc[mi][ni][2]); u.w = f2bf(acc[mi][ni][3]);
                *(ushort4*)(vtout + ((size_t)(bb * 16 + hv) * 64 + dv) * 4096 + nn) = u;
            }
        }
    } else {
#pragma unroll
        for (int mi = 0; mi < 8; ++mi) {
            const int r0 = rowBase + wr * 128 + mi * 16 + lq * 4;
#pragma unroll
            for (int ni = 0; ni < 4; ++ni) {
                const int c = colBase + wc * 64 + ni * 16 + lm;
                float bv = 0.f;
                if (EP == EP_BIAS_ELU_BF16 || EP == EP_BIAS_ADDBF16) bv = bias[c];
#pragma unroll
                for (int r = 0; r < 4; ++r) {
                    const size_t idx = (size_t)(r0 + r) * ldc + c;
                    float v = acc[mi][ni][r] + bv;
                    if (EP == EP_ADDF32) v += addsrc[idx];
                    if (EP == EP_BIAS_ADDBF16) v += bf2f(addb[idx]);
                    if (EP == EP_BIAS_ELU_BF16) v = v > 0.f ? v : (expf(v) - 1.f);
                    if (EP == EP_BF16 || EP == EP_BIAS_ELU_BF16 || EP == EP_QKV) Cb[idx] = f2bf(v);
                    else Cf[idx] = v;
                }
            }
        }
    }
}

// ---------- all weight transposes + f32->bf16 in one dispatch ----------
__global__ __launch_bounds__(256) void transpose_all(
    const float* __restrict__ Wq, const float* __restrict__ Wk,
    const float* __restrict__ Wv, const float* __restrict__ Wo,
    const float* __restrict__ W1, const float* __restrict__ W2,
    unsigned short* WqkvT, unsigned short* WoT,
    unsigned short* W1T, unsigned short* W2T)
{
    __shared__ float t[32][33];
    const int bid = blockIdx.x;
    const float* in;
    unsigned short* out;
    int R, C, tx32, ty32;
    if (bid < 4096) {
        const int job = bid >> 10, tile = bid & 1023;
        ty32 = tile >> 5; tx32 = tile & 31;
        R = 1024; C = 1024;
        if (job == 0)      { in = Wq; out = WqkvT; }
        else if (job == 1) { in = Wk; out = WqkvT + 1024 * 1024; }
        else if (job == 2) { in = Wv; out = WqkvT + 2 * 1024 * 1024; }
        else               { in = Wo; out = WoT; }
    } else if (bid < 8192) {
        const int tile = bid - 4096;           // W1 [1024,4096]: 128 x-tiles, 32 y-tiles
        tx32 = tile & 127; ty32 = tile >> 7;
        R = 1024; C = 4096; in = W1; out = W1T;
    } else {
        const int tile = bid - 8192;           // W2 [4096,1024]: 32 x-tiles, 128 y-tiles
        tx32 = tile & 31; ty32 = tile >> 5;
        R = 4096; C = 1024; in = W2; out = W2T;
    }
    const int c0 = tx32 * 32, r0 = ty32 * 32;
    const int tx = threadIdx.x, ty = threadIdx.y;
#pragma unroll
    for (int j = 0; j < 4; ++j)
        t[ty + j * 8][tx] = in[(size_t)(r0 + ty + j * 8) * C + c0 + tx];
    __syncthreads();
#pragma unroll
    for (int j = 0; j < 4; ++j) {
        int cc = ty + j * 8;
        out[(size_t)(c0 + cc) * R + r0 + tx] = f2bf(t[tx][cc]);
    }
}

__global__ __launch_bounds__(256) void cvt_bf16(const float4* in, ushort4* out) {
    size_t i = (size_t)blockIdx.x * 256 + threadIdx.x;
    float4 v = in[i];
    ushort4 o; o.x = f2bf(v.x); o.y = f2bf(v.y); o.z = f2bf(v.z); o.w = f2bf(v.w);
    out[i] = o;
}

// ---------- FAVOR+ features via MFMA ----------
__global__ __launch_bounds__(256, 2) void feat_mfma(
    const unsigned short* __restrict__ qkvb, const float* __restrict__ proj,
    unsigned short* __restrict__ qf, float* __restrict__ kdash,
    float* __restrict__ diagk, float* __restrict__ bmax)
{
    __shared__ __align__(16) unsigned short sQ[8192];  // [2 ks][128 rows][32 k]
    __shared__ __align__(16) unsigned short sK[8192];
    __shared__ __align__(16) unsigned short sP[4096];  // proj [2 ks][64 m][32 k]
    __shared__ float sdq[128], sdk[128];
    __shared__ float swm[4];
    const int tid = threadIdx.x, w = tid >> 6, l = tid & 63;
    const int t0 = blockIdx.x * 8;
    const int lm = l & 15, lq = l >> 4;

#pragma unroll
    for (int j = 0; j < 4; ++j) {
        const int lt = 2 * w + (j & 1), ks = j >> 1;
        const size_t g = (size_t)(t0 + lt) * 3072 + (l >> 2) * 64 + ks * 32 + (l & 3) * 8;
        async_load16(qkvb + g, sQ + ks * 4096 + lt * 512);
        async_load16(qkvb + g + 1024, sK + ks * 4096 + lt * 512);
    }
    for (int i = tid; i < 4096; i += 256) {
        int m = i >> 6, d = i & 63;
        sP[(d >> 5) * 2048 + m * 32 + (d & 31)] = f2bf(proj[i]);
    }
    __syncthreads();

    {
        int r = tid & 127;
        const unsigned short* src = (tid < 128) ? sQ : sK;
        float s = 0.f;
#pragma unroll
        for (int ks = 0; ks < 2; ++ks) {
            const s16x8* p = (const s16x8*)(src + ks * 4096 + r * 32);
#pragma unroll
            for (int c = 0; c < 4; ++c) {
                s16x8 v = p[c];
#pragma unroll
                for (int e = 0; e < 8; ++e) { float f = bf2f((unsigned short)v[e]); s += f * f; }
            }
        }
        if (tid < 128) sdq[r] = s * 0.0625f; else sdk[r] = s * 0.0625f;
    }
    __syncthreads();

    s16x8 pf2[2][4];
#pragma unroll
    for (int ks = 0; ks < 2; ++ks)
#pragma unroll
        for (int ni = 0; ni < 4; ++ni)
            pf2[ks][ni] = *(const s16x8*)(sP + ks * 2048 + (ni * 16 + lm) * 32 + lq * 8);
    f32x4 qa[2][4] = {}, ka[2][4] = {};
#pragma unroll
    for (int i = 0; i < 2; ++i) {
        const int rowt = (w * 2 + i) * 16 + lm;
#pragma unroll
        for (int ks = 0; ks < 2; ++ks) {
            s16x8 aq = *(const s16x8*)(sQ + ks * 4096 + rowt * 32 + lq * 8);
            s16x8 ak = *(const s16x8*)(sK + ks * 4096 + rowt * 32 + lq * 8);
#pragma unroll
            for (int ni = 0; ni < 4; ++ni) {
                qa[i][ni] = __builtin_amdgcn_mfma_f32_16x16x32_bf16(aq, pf2[ks][ni], qa[i][ni], 0, 0, 0);
                ka[i][ni] = __builtin_amdgcn_mfma_f32_16x16x32_bf16(ak, pf2[ks][ni], ka[i][ni], 0, 0, 0);
            }
        }
    }

    const float dn = 0.35355339059327373f;
    float kmax = -3.0e38f;
#pragma unroll
    for (int i = 0; i < 2; ++i) {
#pragma unroll
        for (int r = 0; r < 4; ++r) {
            const int row = (w * 2 + i) * 16 + lq * 4 + r;
            float q0 = qa[i][0][r] * dn, q1 = qa[i][1][r] * dn;
            float q2 = qa[i][2][r] * dn, q3 = qa[i][3][r] * dn;
            float mq = fmaxf(fmaxf(q0, q1), fmaxf(q2, q3));
#pragma unroll
            for (int o = 1; o < 16; o <<= 1) mq = fmaxf(mq, __shfl_xor(mq, o, 64));
            const float dg = sdq[row];
            const size_t ob = (size_t)t0 * 1024 + (size_t)row * 64 + lm;
            qf[ob]      = f2bf(0.125f * (expf(q0 - dg - mq) + 1e-6f));
            qf[ob + 16] = f2bf(0.125f * (expf(q1 - dg - mq) + 1e-6f));
            qf[ob + 32] = f2bf(0.125f * (expf(q2 - dg - mq) + 1e-6f));
            qf[ob + 48] = f2bf(0.125f * (expf(q3 - dg - mq) + 1e-6f));
#pragma unroll
            for (int ni = 0; ni < 4; ++ni) {
                float kd = ka[i][ni][r] * dn;
                kdash[ob + ni * 16] = kd;
                kmax = fmaxf(kmax, kd);
            }
        }
    }
    kmax = wave_max(kmax);
    if (l == 0) swm[w] = kmax;
    __syncthreads();
    if (tid < 128) diagk[t0 * 16 + tid] = sdk[tid];
    if (tid == 0) bmax[blockIdx.x] = fmaxf(fmaxf(swm[0], swm[1]), fmaxf(swm[2], swm[3]));
}

__global__ __launch_bounds__(256) void max_reduce(const float* bm, float* mx) {
    const int tid = threadIdx.x;
    float m = -3.0e38f;
    for (int i = tid; i < 2048; i += 256) m = fmaxf(m, bm[i]);
    m = wave_max(m);
    __shared__ float s[4];
    if ((tid & 63) == 0) s[tid >> 6] = m;
    __syncthreads();
    if (tid == 0) mx[0] = fmaxf(fmaxf(s[0], s[1]), fmaxf(s[2], s[3]));
}

// ---------- fused kf + kv/ksum via MFMA ----------
__global__ __launch_bounds__(256, 2) void kv_fused(
    const float* __restrict__ kdash, const float* __restrict__ diagk,
    const float* __restrict__ mx, const unsigned short* __restrict__ vT,
    float* kv, float* ksum)
{
    __shared__ __align__(16) unsigned short sKF[64 * 72];
    __shared__ __align__(16) unsigned short sV[64 * 72];
    __shared__ float sDiag[1024];
    const int tid = threadIdx.x, w = tid >> 6, l = tid & 63;
    const int bh = blockIdx.x, b = bh >> 4, h = bh & 15;
    const int n0 = blockIdx.y * 1024;
    const int lm = l & 15, lq = l >> 4;
    const float mxv = mx[0];

    for (int i = tid; i < 1024; i += 256)
        sDiag[i] = diagk[(size_t)(b * 4096 + n0 + i) * 16 + h] + mxv;

    s16x8 onesf;
    {
        short ov = (lm == 0) ? (short)0x3F80 : (short)0;
#pragma unroll
        for (int j = 0; j < 8; ++j) onesf[j] = ov;
    }
    f32x4 acc[4] = {};
    f32x4 accS = {};
    __syncthreads();

    for (int c0 = 0; c0 < 1024; c0 += 64) {
        __syncthreads();
        {
            const int n = c0 + l;
            const size_t krow = ((size_t)(b * 4096 + n0 + n)) * 1024 + h * 64 + w * 16;
            const float4* kp = (const float4*)(kdash + krow);
            float4 k0 = kp[0], k1 = kp[1], k2 = kp[2], k3 = kp[3];
            const float dg = sDiag[n];
            float vv[16] = {k0.x, k0.y, k0.z, k0.w, k1.x, k1.y, k1.z, k1.w,
                            k2.x, k2.y, k2.z, k2.w, k3.x, k3.y, k3.z, k3.w};
            unsigned short* dst = sKF + (w * 16) * 72 + l;
#pragma unroll
            for (int e = 0; e < 16; ++e)
                dst[e * 72] = f2bf(0.125f * (expf(vv[e] - dg) + 1e-6f));
        }
        {
            const int d = tid >> 2, nq = tid & 3;
            const uint4* vp = (const uint4*)(vT + ((size_t)bh * 64 + d) * 4096 + n0 + c0 + nq * 16);
            uint4 v0 = vp[0], v1 = vp[1];
            uint4* ldst = (uint4*)(sV + d * 72 + nq * 16);
            ldst[0] = v0; ldst[1] = v1;
        }
        __syncthreads();
#pragma unroll
        for (int ks = 0; ks < 2; ++ks) {
            s16x8 a = *(const s16x8*)(sKF + (w * 16 + lm) * 72 + ks * 32 + lq * 8);
            accS = __builtin_amdgcn_mfma_f32_16x16x32_bf16(a, onesf, accS, 0, 0, 0);
#pragma unroll
            for (int ni = 0; ni < 4; ++ni) {
                s16x8 bf = *(const s16x8*)(sV + (ni * 16 + lm) * 72 + ks * 32 + lq * 8);
                acc[ni] = __builtin_amdgcn_mfma_f32_16x16x32_bf16(a, bf, acc[ni], 0, 0, 0);
            }
        }
    }

    const size_t kvbase = (size_t)bh * 4096;
#pragma unroll
    for (int ni = 0; ni < 4; ++ni)
#pragma unroll
        for (int r = 0; r < 4; ++r)
            atomicAdd(kv + kvbase + (size_t)(w * 16 + lq * 4 + r) * 64 + ni * 16 + lm, acc[ni][r]);
    if (lm == 0)
#pragma unroll
        for (int r = 0; r < 4; ++r)
            atomicAdd(ksum + bh * 64 + w * 16 + lq * 4 + r, accS[r]);
}

// ---------- attention combine via MFMA, den folded as output column 64 ----------
__global__ __launch_bounds__(256, 2) void attn_mfma(const unsigned short* __restrict__ qf,
                                                    const float* __restrict__ kv,
                                                    const float* __restrict__ ksum,
                                                    unsigned short* __restrict__ attn) {
    __shared__ __align__(16) unsigned short sA[8192];  // [2 ks][128 rows][32 m]
    __shared__ __align__(16) unsigned short sB[5120];  // [2 ks][80 cols][32 m]; col64=ksum
    const int tid = threadIdx.x, w = tid >> 6, l = tid & 63;
    const int bh = blockIdx.x, b = bh >> 4, h = bh & 15;
    const int n0 = blockIdx.y * 128;
    const int lm = l & 15, lq = l >> 4;

#pragma unroll
    for (int j = 0; j < 4; ++j) {
        const int r0 = w * 32 + (j & 1) * 16, ks = j >> 1;
        const size_t g = (size_t)(b * 4096 + n0 + r0 + (l >> 2)) * 1024 + h * 64 + ks * 32 + (l & 3) * 8;
        async_load16(qf + g, sA + ks * 4096 + r0 * 32);
    }
    for (int i = tid; i < 5120; i += 256) sB[i] = 0;
    __syncthreads();
    for (int i = tid; i < 4096; i += 256) {
        int m = i >> 6, d = i & 63;
        sB[(m >> 5) * 2560 + d * 32 + (m & 31)] = f2bf(kv[(size_t)bh * 4096 + i]);
    }
    if (tid < 64) {
        int m = tid;
        sB[(m >> 5) * 2560 + 64 * 32 + (m & 31)] = f2bf(ksum[bh * 64 + m]);
    }
    __syncthreads();

    s16x8 bf2r[2][5];
#pragma unroll
    for (int ks = 0; ks < 2; ++ks)
#pragma unroll
        for (int ni = 0; ni < 5; ++ni)
            bf2r[ks][ni] = *(const s16x8*)(sB + ks * 2560 + (ni * 16 + lm) * 32 + lq * 8);
    f32x4 acc[2][5] = {};
#pragma unroll
    for (int i = 0; i < 2; ++i) {
        const int rowt = (w * 2 + i) * 16 + lm;
#pragma unroll
        for (int ks = 0; ks < 2; ++ks) {
            s16x8 a = *(const s16x8*)(sA + ks * 4096 + rowt * 32 + lq * 8);
#pragma unroll
            for (int ni = 0; ni < 5; ++ni)
                acc[i][ni] = __builtin_amdgcn_mfma_f32_16x16x32_bf16(a, bf2r[ks][ni], acc[i][ni], 0, 0, 0);
        }
    }
#pragma unroll
    for (int i = 0; i < 2; ++i) {
#pragma unroll
        for (int r = 0; r < 4; ++r) {
            const int row = (w * 2 + i) * 16 + lq * 4 + r;
            float den = __shfl(acc[i][4][r], l & 48, 64);
            float rd = 1.f / den;
            const size_t ob = (size_t)(b * 4096 + n0 + row) * 1024 + h * 64 + lm;
            attn[ob]      = f2bf(acc[i][0][r] * rd);
            attn[ob + 16] = f2bf(acc[i][1][r] * rd);
            attn[ob + 32] = f2bf(acc[i][2][r] * rd);
            attn[ob + 48] = f2bf(acc[i][3][r] * rd);
        }
    }
}

// ---------- LayerNorm (D=1024) ----------
__device__ __forceinline__ float block_sum256(float v, float* sbuf, int tid) {
    v = wave_sum(v);
    __syncthreads();
    if ((tid & 63) == 0) sbuf[tid >> 6] = v;
    __syncthreads();
    return sbuf[0] + sbuf[1] + sbuf[2] + sbuf[3];
}

template <int WF32, int WBF16>
__global__ __launch_bounds__(256) void ln_kernel(const float* src, const float* g, const float* b,
                                                 float* dstf, unsigned short* dstb) {
    __shared__ float sbuf[4];
    const int t = blockIdx.x, tid = threadIdx.x;
    float4 v = ((const float4*)(src + (size_t)t * 1024))[tid];
    float mu = block_sum256(v.x + v.y + v.z + v.w, sbuf, tid) * (1.f / 1024.f);
    float dx = v.x - mu, dy = v.y - mu, dz = v.z - mu, dw = v.w - mu;
    float var = block_sum256(dx * dx + dy * dy + dz * dz + dw * dw, sbuf, tid) * (1.f / 1024.f);
    float r = rsqrtf(var + 1e-6f);
    float4 gv = ((const float4*)g)[tid];
    float4 bv = ((const float4*)b)[tid];
    float4 o;
    o.x = dx * r * gv.x + bv.x; o.y = dy * r * gv.y + bv.y;
    o.z = dz * r * gv.z + bv.z; o.w = dw * r * gv.w + bv.w;
    if (WF32) ((float4*)(dstf + (size_t)t * 1024))[tid] = o;
    if (WBF16) {
        ushort4 u; u.x = f2bf(o.x); u.y = f2bf(o.y); u.z = f2bf(o.z); u.w = f2bf(o.w);
        ((ushort4*)(dstb + (size_t)t * 1024))[tid] = u;
    }
}

// ---------- launcher ----------
extern "C" void kernel_launch(void* const* d_in, const int* in_sizes, int n_in,
                              void* d_out, int out_size, void* d_ws, size_t ws_size,
                              hipStream_t stream) {
    (void)in_sizes; (void)n_in; (void)out_size; (void)ws_size;
    const float* x    = (const float*)d_in[0];
    const float* Wq   = (const float*)d_in[1];
    const float* Wk   = (const float*)d_in[2];
    const float* Wv   = (const float*)d_in[3];
    const float* Wo   = (const float*)d_in[4];
    const float* proj = (const float*)d_in[5];
    const float* W1   = (const float*)d_in[6];
    const float* b1   = (const float*)d_in[7];
    const float* W2   = (const float*)d_in[8];
    const float* b2   = (const float*)d_in[9];
    const float* g1   = (const float*)d_in[10];
    const float* lb1  = (const float*)d_in[11];
    const float* g2   = (const float*)d_in[12];
    const float* lb2  = (const float*)d_in[13];

    char* ws = (char*)d_ws;
    size_t off = 0;
    auto alloc = [&](size_t bytes) { char* p = ws + off; off += (bytes + 255) & ~(size_t)255; return p; };
    unsigned short* WqkvT = (unsigned short*)alloc((size_t)3072 * 1024 * 2);
    unsigned short* WoT   = (unsigned short*)alloc((size_t)1024 * 1024 * 2);
    unsigned short* W1T   = (unsigned short*)alloc((size_t)4096 * 1024 * 2);
    unsigned short* W2T   = (unsigned short*)alloc((size_t)1024 * 4096 * 2);
    unsigned short* xb    = (unsigned short*)alloc((size_t)16384 * 1024 * 2);  // later: attn
    unsigned short* qkvb  = (unsigned short*)alloc((size_t)16384 * 3072 * 2);  // later: out1b + h(lo)
    unsigned short* qf    = (unsigned short*)alloc((size_t)16384 * 1024 * 2);  // later: h(mid)
    unsigned short* vT    = (unsigned short*)alloc((size_t)16384 * 1024 * 2);  // later: h(hi)
    float* kv    = (float*)alloc((size_t)64 * 64 * 64 * 4);
    float* ksum  = (float*)alloc((size_t)64 * 64 * 4);
    float* diagk = (float*)alloc((size_t)16384 * 16 * 4);
    float* bmax  = (float*)alloc((size_t)16384 * 4);
    float* mx    = (float*)alloc(256);

    unsigned short* attnb = xb;
    unsigned short* out1b = qkvb;                                   // 32 MB
    unsigned short* h     = qkvb + (size_t)16384 * 1024;            // 128 MB (qkvb hi + qf + vT)
    float* kdash = (float*)d_out;               // d_out doubles as fp32 scratch
    float* preLN = (float*)d_out;

    transpose_all<<<12288, dim3(32, 8), 0, stream>>>(Wq, Wk, Wv, Wo, W1, W2,
                                                     WqkvT, WoT, W1T, W2T);
    cvt_bf16<<<16384, 256, 0, stream>>>((const float4*)x, (ushort4*)xb);

    // QKV: [16384,1024] x [1024,3072]; Q,K -> qkvb (bf16), V -> vT (transposed)
    gemm256<EP_QKV><<<dim3(12, 64), 512, 0, stream>>>(xb, 1024, WqkvT, 1024, 1024, 3072,
                                                      nullptr, qkvb, nullptr, nullptr, nullptr, vT);
    feat_mfma<<<2048, 256, 0, stream>>>(qkvb, proj, qf, kdash, diagk, bmax);
    max_reduce<<<1, 256, 0, stream>>>(bmax, mx);
    hipMemsetAsync(kv, 0, (size_t)64 * 64 * 64 * 4 + (size_t)64 * 64 * 4, stream);
    kv_fused<<<dim3(64, 4), 256, 0, stream>>>(kdash, diagk, mx, vT, kv, ksum);
    attn_mfma<<<dim3(64, 32), 256, 0, stream>>>(qf, kv, ksum, attnb);
    // attn @ Wo + x -> preLN1 (in d_out)
    gemm256<EP_ADDF32><<<dim3(4, 64), 512, 0, stream>>>(attnb, 1024, WoT, 1024, 1024, 1024,
                                                        preLN, nullptr, nullptr, x, nullptr, nullptr);
    ln_kernel<0, 1><<<16384, 256, 0, stream>>>(preLN, g1, lb1, nullptr, out1b);
    // FFN full-DFF: h = elu(out1b @ W1 + b1)  [16384,4096]
    gemm256<EP_BIAS_ELU_BF16><<<dim3(16, 64), 512, 0, stream>>>(out1b, 1024, W1T, 1024, 1024, 4096,
                                                                nullptr, h, b1, nullptr, nullptr, nullptr);
    // preLN2 = h @ W2 + b2 + out1  (K=4096)
    gemm256<EP_BIAS_ADDBF16><<<dim3(4, 64), 512, 0, stream>>>(h, 4096, W2T, 4096, 4096, 1024,
                                                              preLN, nullptr, b2, nullptr, out1b, nullptr);
    ln_kernel<1, 0><<<16384, 256, 0, stream>>>(preLN, g2, lb2, (float*)d_out, nullptr);
}

// Round 6
// 852.911 us; speedup vs baseline: 1.1915x; 1.0131x over previous
//
#include <hip/hip_runtime.h>
#include <math.h>

// ---------- types / helpers ----------
typedef __attribute__((ext_vector_type(8))) short s16x8;
typedef __attribute__((ext_vector_type(4))) float f32x4;

__device__ __forceinline__ float bf2f(unsigned short u) {
    union { unsigned int i; float f; } c; c.i = ((unsigned int)u) << 16; return c.f;
}
__device__ __forceinline__ unsigned short f2bf(float f) {
    union { float f; unsigned int i; } c; c.f = f;
    unsigned int r = c.i + 0x7fffu + ((c.i >> 16) & 1u);
    return (unsigned short)(r >> 16);
}
__device__ __forceinline__ float wave_sum(float v) {
#pragma unroll
    for (int o = 32; o; o >>= 1) v += __shfl_xor(v, o, 64);
    return v;
}
__device__ __forceinline__ float wave_max(float v) {
#pragma unroll
    for (int o = 32; o; o >>= 1) v = fmaxf(v, __shfl_xor(v, o, 64));
    return v;
}
__device__ __forceinline__ void async_load16(const void* g, void* l) {
    __builtin_amdgcn_global_load_lds(
        (const __attribute__((address_space(1))) unsigned int*)g,
        (__attribute__((address_space(3))) unsigned int*)l, 16, 0, 0);
}

// ---------- bf16 GEMM: C[M,N] = A[M,K] * BT[N,K]^T, 128x128 tile ----------
// r1-proven structure (834 us total). Only change vs r1: __launch_bounds__(256,4)
// -> 4 blocks/CU so cross-block overlap (m114) absorbs the per-block
// vmcnt(0)+barrier drain. LDS 4x32KB=128KB <= 160KB; VGPR ~56 << 128 cap.
enum { EP_BF16 = 0, EP_ADDF32 = 1, EP_BIAS_ELU_BF16 = 2, EP_QKV = 4, EP_BIAS_ADDBF16 = 5 };

template <int EP>
__global__ __launch_bounds__(256, 4) void gemm_bt(
    const unsigned short* __restrict__ A, int lda,
    const unsigned short* __restrict__ BT, int ldb,
    int K, int ldc,
    float* Cf, unsigned short* Cb,
    const float* __restrict__ bias, const float* addsrc,
    const unsigned short* __restrict__ addb,
    unsigned short* vtout)
{
    __shared__ __align__(16) unsigned short sA[128 * 32];
    __shared__ __align__(16) unsigned short sB[128 * 32];
    const int tid = threadIdx.x;
    const int w = tid >> 6, l = tid & 63;
    const int wm = w & 1, wn = w >> 1;

    // XCD-chunked bijective swizzle (nwg % 8 == 0 for all our grids)
    unsigned int i = blockIdx.y * gridDim.x + blockIdx.x;
    const unsigned int chunk = (gridDim.x * gridDim.y) >> 3;
    i = (i & 7u) * chunk + (i >> 3);
    const int tileX = i % gridDim.x, tileY = i / gridDim.x;
    const int rowBase = tileY * 128, colBase = tileX * 128;

    f32x4 acc[4][4] = {};

    const int sr = w * 32 + (l >> 2);
    const int sc = (l & 3) * 8;
    const unsigned short* gA0 = A + (size_t)(rowBase + sr) * lda + sc;
    const unsigned short* gA1 = gA0 + (size_t)16 * lda;
    const unsigned short* gB0 = BT + (size_t)(colBase + sr) * ldb + sc;
    const unsigned short* gB1 = gB0 + (size_t)16 * ldb;
    unsigned short* lA0 = sA + (w * 32) * 32;
    unsigned short* lA1 = sA + (w * 32 + 16) * 32;
    unsigned short* lB0 = sB + (w * 32) * 32;
    unsigned short* lB1 = sB + (w * 32 + 16) * 32;

    const int lm = l & 15, lq = l >> 4;
    const int aoff = (wm * 64 + lm) * 32 + lq * 8;
    const int boff = (wn * 64 + lm) * 32 + lq * 8;

    for (int k0 = 0; k0 < K; k0 += 32) {
        __syncthreads();
        async_load16(gA0 + k0, lA0);
        async_load16(gA1 + k0, lA1);
        async_load16(gB0 + k0, lB0);
        async_load16(gB1 + k0, lB1);
        __syncthreads();
        s16x8 af[4], bfr[4];
#pragma unroll
        for (int mi = 0; mi < 4; ++mi) af[mi] = *(const s16x8*)(sA + aoff + mi * 512);
#pragma unroll
        for (int ni = 0; ni < 4; ++ni) bfr[ni] = *(const s16x8*)(sB + boff + ni * 512);
#pragma unroll
        for (int mi = 0; mi < 4; ++mi)
#pragma unroll
            for (int ni = 0; ni < 4; ++ni)
                acc[mi][ni] = __builtin_amdgcn_mfma_f32_16x16x32_bf16(
                    af[mi], bfr[ni], acc[mi][ni], 0, 0, 0);
    }

    if (EP == EP_QKV && colBase >= 2048) {
        // write V part transposed: vT[(b*16+h)*64+d][n], 4 consecutive tokens -> ushort4
#pragma unroll
        for (int mi = 0; mi < 4; ++mi) {
            const int row0 = rowBase + wm * 64 + mi * 16 + lq * 4;
            const int bb = row0 >> 12, nn = row0 & 4095;
#pragma unroll
            for (int ni = 0; ni < 4; ++ni) {
                const int c = colBase + wn * 64 + ni * 16 + lm - 2048;
                const int hv = c >> 6, dv = c & 63;
                ushort4 u;
                u.x = f2bf(acc[mi][ni][0]); u.y = f2bf(acc[mi][ni][1]);
                u.z = f2bf(acc[mi][ni][2]); u.w = f2bf(acc[mi][ni][3]);
                *(ushort4*)(vtout + ((size_t)(bb * 16 + hv) * 64 + dv) * 4096 + nn) = u;
            }
        }
    } else {
#pragma unroll
        for (int mi = 0; mi < 4; ++mi) {
            const int r0 = rowBase + wm * 64 + mi * 16 + lq * 4;
#pragma unroll
            for (int ni = 0; ni < 4; ++ni) {
                const int c = colBase + wn * 64 + ni * 16 + lm;
                float bv = 0.f;
                if (EP == EP_BIAS_ELU_BF16 || EP == EP_BIAS_ADDBF16) bv = bias[c];
#pragma unroll
                for (int r = 0; r < 4; ++r) {
                    const size_t idx = (size_t)(r0 + r) * ldc + c;
                    float v = acc[mi][ni][r] + bv;
                    if (EP == EP_ADDF32) v += addsrc[idx];
                    if (EP == EP_BIAS_ADDBF16) v += bf2f(addb[idx]);
                    if (EP == EP_BIAS_ELU_BF16) v = v > 0.f ? v : (expf(v) - 1.f);
                    if (EP == EP_BF16 || EP == EP_BIAS_ELU_BF16 || EP == EP_QKV) Cb[idx] = f2bf(v);
                    else Cf[idx] = v;
                }
            }
        }
    }
}

// ---------- all weight transposes + f32->bf16 in one dispatch ----------
__global__ __launch_bounds__(256) void transpose_all(
    const float* __restrict__ Wq, const float* __restrict__ Wk,
    const float* __restrict__ Wv, const float* __restrict__ Wo,
    const float* __restrict__ W1, const float* __restrict__ W2,
    unsigned short* WqkvT, unsigned short* WoT,
    unsigned short* W1T, unsigned short* W2T)
{
    __shared__ float t[32][33];
    const int bid = blockIdx.x;
    const float* in;
    unsigned short* out;
    int R, C, tx32, ty32;
    if (bid < 4096) {
        const int job = bid >> 10, tile = bid & 1023;
        ty32 = tile >> 5; tx32 = tile & 31;
        R = 1024; C = 1024;
        if (job == 0)      { in = Wq; out = WqkvT; }
        else if (job == 1) { in = Wk; out = WqkvT + 1024 * 1024; }
        else if (job == 2) { in = Wv; out = WqkvT + 2 * 1024 * 1024; }
        else               { in = Wo; out = WoT; }
    } else if (bid < 8192) {
        const int tile = bid - 4096;           // W1 [1024,4096]: 128 x-tiles, 32 y-tiles
        tx32 = tile & 127; ty32 = tile >> 7;
        R = 1024; C = 4096; in = W1; out = W1T;
    } else {
        const int tile = bid - 8192;           // W2 [4096,1024]: 32 x-tiles, 128 y-tiles
        tx32 = tile & 31; ty32 = tile >> 5;
        R = 4096; C = 1024; in = W2; out = W2T;
    }
    const int c0 = tx32 * 32, r0 = ty32 * 32;
    const int tx = threadIdx.x, ty = threadIdx.y;
#pragma unroll
    for (int j = 0; j < 4; ++j)
        t[ty + j * 8][tx] = in[(size_t)(r0 + ty + j * 8) * C + c0 + tx];
    __syncthreads();
#pragma unroll
    for (int j = 0; j < 4; ++j) {
        int cc = ty + j * 8;
        out[(size_t)(c0 + cc) * R + r0 + tx] = f2bf(t[tx][cc]);
    }
}

__global__ __launch_bounds__(256) void cvt_bf16(const float4* in, ushort4* out) {
    size_t i = (size_t)blockIdx.x * 256 + threadIdx.x;
    float4 v = in[i];
    ushort4 o; o.x = f2bf(v.x); o.y = f2bf(v.y); o.z = f2bf(v.z); o.w = f2bf(v.w);
    out[i] = o;
}

// ---------- FAVOR+ features via MFMA ----------
__global__ __launch_bounds__(256, 2) void feat_mfma(
    const unsigned short* __restrict__ qkvb, const float* __restrict__ proj,
    unsigned short* __restrict__ qf, float* __restrict__ kdash,
    float* __restrict__ diagk, float* __restrict__ bmax)
{
    __shared__ __align__(16) unsigned short sQ[8192];  // [2 ks][128 rows][32 k]
    __shared__ __align__(16) unsigned short sK[8192];
    __shared__ __align__(16) unsigned short sP[4096];  // proj [2 ks][64 m][32 k]
    __shared__ float sdq[128], sdk[128];
    __shared__ float swm[4];
    const int tid = threadIdx.x, w = tid >> 6, l = tid & 63;
    const int t0 = blockIdx.x * 8;
    const int lm = l & 15, lq = l >> 4;

#pragma unroll
    for (int j = 0; j < 4; ++j) {
        const int lt = 2 * w + (j & 1), ks = j >> 1;
        const size_t g = (size_t)(t0 + lt) * 3072 + (l >> 2) * 64 + ks * 32 + (l & 3) * 8;
        async_load16(qkvb + g, sQ + ks * 4096 + lt * 512);
        async_load16(qkvb + g + 1024, sK + ks * 4096 + lt * 512);
    }
    for (int i = tid; i < 4096; i += 256) {
        int m = i >> 6, d = i & 63;
        sP[(d >> 5) * 2048 + m * 32 + (d & 31)] = f2bf(proj[i]);
    }
    __syncthreads();

    {
        int r = tid & 127;
        const unsigned short* src = (tid < 128) ? sQ : sK;
        float s = 0.f;
#pragma unroll
        for (int ks = 0; ks < 2; ++ks) {
            const s16x8* p = (const s16x8*)(src + ks * 4096 + r * 32);
#pragma unroll
            for (int c = 0; c < 4; ++c) {
                s16x8 v = p[c];
#pragma unroll
                for (int e = 0; e < 8; ++e) { float f = bf2f((unsigned short)v[e]); s += f * f; }
            }
        }
        if (tid < 128) sdq[r] = s * 0.0625f; else sdk[r] = s * 0.0625f;
    }
    __syncthreads();

    s16x8 pf2[2][4];
#pragma unroll
    for (int ks = 0; ks < 2; ++ks)
#pragma unroll
        for (int ni = 0; ni < 4; ++ni)
            pf2[ks][ni] = *(const s16x8*)(sP + ks * 2048 + (ni * 16 + lm) * 32 + lq * 8);
    f32x4 qa[2][4] = {}, ka[2][4] = {};
#pragma unroll
    for (int i = 0; i < 2; ++i) {
        const int rowt = (w * 2 + i) * 16 + lm;
#pragma unroll
        for (int ks = 0; ks < 2; ++ks) {
            s16x8 aq = *(const s16x8*)(sQ + ks * 4096 + rowt * 32 + lq * 8);
            s16x8 ak = *(const s16x8*)(sK + ks * 4096 + rowt * 32 + lq * 8);
#pragma unroll
            for (int ni = 0; ni < 4; ++ni) {
                qa[i][ni] = __builtin_amdgcn_mfma_f32_16x16x32_bf16(aq, pf2[ks][ni], qa[i][ni], 0, 0, 0);
                ka[i][ni] = __builtin_amdgcn_mfma_f32_16x16x32_bf16(ak, pf2[ks][ni], ka[i][ni], 0, 0, 0);
            }
        }
    }

    const float dn = 0.35355339059327373f;
    float kmax = -3.0e38f;
#pragma unroll
    for (int i = 0; i < 2; ++i) {
#pragma unroll
        for (int r = 0; r < 4; ++r) {
            const int row = (w * 2 + i) * 16 + lq * 4 + r;
            float q0 = qa[i][0][r] * dn, q1 = qa[i][1][r] * dn;
            float q2 = qa[i][2][r] * dn, q3 = qa[i][3][r] * dn;
            float mq = fmaxf(fmaxf(q0, q1), fmaxf(q2, q3));
#pragma unroll
            for (int o = 1; o < 16; o <<= 1) mq = fmaxf(mq, __shfl_xor(mq, o, 64));
            const float dg = sdq[row];
            const size_t ob = (size_t)t0 * 1024 + (size_t)row * 64 + lm;
            qf[ob]      = f2bf(0.125f * (expf(q0 - dg - mq) + 1e-6f));
            qf[ob + 16] = f2bf(0.125f * (expf(q1 - dg - mq) + 1e-6f));
            qf[ob + 32] = f2bf(0.125f * (expf(q2 - dg - mq) + 1e-6f));
            qf[ob + 48] = f2bf(0.125f * (expf(q3 - dg - mq) + 1e-6f));
#pragma unroll
            for (int ni = 0; ni < 4; ++ni) {
                float kd = ka[i][ni][r] * dn;
                kdash[ob + ni * 16] = kd;
                kmax = fmaxf(kmax, kd);
            }
        }
    }
    kmax = wave_max(kmax);
    if (l == 0) swm[w] = kmax;
    __syncthreads();
    if (tid < 128) diagk[t0 * 16 + tid] = sdk[tid];
    if (tid == 0) bmax[blockIdx.x] = fmaxf(fmaxf(swm[0], swm[1]), fmaxf(swm[2], swm[3]));
}

__global__ __launch_bounds__(256) void max_reduce(const float* bm, float* mx) {
    const int tid = threadIdx.x;
    float m = -3.0e38f;
    for (int i = tid; i < 2048; i += 256) m = fmaxf(m, bm[i]);
    m = wave_max(m);
    __shared__ float s[4];
    if ((tid & 63) == 0) s[tid >> 6] = m;
    __syncthreads();
    if (tid == 0) mx[0] = fmaxf(fmaxf(s[0], s[1]), fmaxf(s[2], s[3]));
}

// ---------- fused kf + kv/ksum via MFMA ----------
__global__ __launch_bounds__(256, 2) void kv_fused(
    const float* __restrict__ kdash, const float* __restrict__ diagk,
    const float* __restrict__ mx, const unsigned short* __restrict__ vT,
    float* kv, float* ksum)
{
    __shared__ __align__(16) unsigned short sKF[64 * 72];
    __shared__ __align__(16) unsigned short sV[64 * 72];
    __shared__ float sDiag[1024];
    const int tid = threadIdx.x, w = tid >> 6, l = tid & 63;
    const int bh = blockIdx.x, b = bh >> 4, h = bh & 15;
    const int n0 = blockIdx.y * 1024;
    const int lm = l & 15, lq = l >> 4;
    const float mxv = mx[0];

    for (int i = tid; i < 1024; i += 256)
        sDiag[i] = diagk[(size_t)(b * 4096 + n0 + i) * 16 + h] + mxv;

    s16x8 onesf;
    {
        short ov = (lm == 0) ? (short)0x3F80 : (short)0;
#pragma unroll
        for (int j = 0; j < 8; ++j) onesf[j] = ov;
    }
    f32x4 acc[4] = {};
    f32x4 accS = {};
    __syncthreads();

    for (int c0 = 0; c0 < 1024; c0 += 64) {
        __syncthreads();
        {
            const int n = c0 + l;
            const size_t krow = ((size_t)(b * 4096 + n0 + n)) * 1024 + h * 64 + w * 16;
            const float4* kp = (const float4*)(kdash + krow);
            float4 k0 = kp[0], k1 = kp[1], k2 = kp[2], k3 = kp[3];
            const float dg = sDiag[n];
            float vv[16] = {k0.x, k0.y, k0.z, k0.w, k1.x, k1.y, k1.z, k1.w,
                            k2.x, k2.y, k2.z, k2.w, k3.x, k3.y, k3.z, k3.w};
            unsigned short* dst = sKF + (w * 16) * 72 + l;
#pragma unroll
            for (int e = 0; e < 16; ++e)
                dst[e * 72] = f2bf(0.125f * (expf(vv[e] - dg) + 1e-6f));
        }
        {
            const int d = tid >> 2, nq = tid & 3;
            const uint4* vp = (const uint4*)(vT + ((size_t)bh * 64 + d) * 4096 + n0 + c0 + nq * 16);
            uint4 v0 = vp[0], v1 = vp[1];
            uint4* ldst = (uint4*)(sV + d * 72 + nq * 16);
            ldst[0] = v0; ldst[1] = v1;
        }
        __syncthreads();
#pragma unroll
        for (int ks = 0; ks < 2; ++ks) {
            s16x8 a = *(const s16x8*)(sKF + (w * 16 + lm) * 72 + ks * 32 + lq * 8);
            accS = __builtin_amdgcn_mfma_f32_16x16x32_bf16(a, onesf, accS, 0, 0, 0);
#pragma unroll
            for (int ni = 0; ni < 4; ++ni) {
                s16x8 bf = *(const s16x8*)(sV + (ni * 16 + lm) * 72 + ks * 32 + lq * 8);
                acc[ni] = __builtin_amdgcn_mfma_f32_16x16x32_bf16(a, bf, acc[ni], 0, 0, 0);
            }
        }
    }

    const size_t kvbase = (size_t)bh * 4096;
#pragma unroll
    for (int ni = 0; ni < 4; ++ni)
#pragma unroll
        for (int r = 0; r < 4; ++r)
            atomicAdd(kv + kvbase + (size_t)(w * 16 + lq * 4 + r) * 64 + ni * 16 + lm, acc[ni][r]);
    if (lm == 0)
#pragma unroll
        for (int r = 0; r < 4; ++r)
            atomicAdd(ksum + bh * 64 + w * 16 + lq * 4 + r, accS[r]);
}

// ---------- attention combine via MFMA, den folded as output column 64 ----------
__global__ __launch_bounds__(256, 2) void attn_mfma(const unsigned short* __restrict__ qf,
                                                    const float* __restrict__ kv,
                                                    const float* __restrict__ ksum,
                                                    unsigned short* __restrict__ attn) {
    __shared__ __align__(16) unsigned short sA[8192];  // [2 ks][128 rows][32 m]
    __shared__ __align__(16) unsigned short sB[5120];  // [2 ks][80 cols][32 m]; col64=ksum
    const int tid = threadIdx.x, w = tid >> 6, l = tid & 63;
    const int bh = blockIdx.x, b = bh >> 4, h = bh & 15;
    const int n0 = blockIdx.y * 128;
    const int lm = l & 15, lq = l >> 4;

#pragma unroll
    for (int j = 0; j < 4; ++j) {
        const int r0 = w * 32 + (j & 1) * 16, ks = j >> 1;
        const size_t g = (size_t)(b * 4096 + n0 + r0 + (l >> 2)) * 1024 + h * 64 + ks * 32 + (l & 3) * 8;
        async_load16(qf + g, sA + ks * 4096 + r0 * 32);
    }
    for (int i = tid; i < 5120; i += 256) sB[i] = 0;
    __syncthreads();
    for (int i = tid; i < 4096; i += 256) {
        int m = i >> 6, d = i & 63;
        sB[(m >> 5) * 2560 + d * 32 + (m & 31)] = f2bf(kv[(size_t)bh * 4096 + i]);
    }
    if (tid < 64) {
        int m = tid;
        sB[(m >> 5) * 2560 + 64 * 32 + (m & 31)] = f2bf(ksum[bh * 64 + m]);
    }
    __syncthreads();

    s16x8 bf2r[2][5];
#pragma unroll
    for (int ks = 0; ks < 2; ++ks)
#pragma unroll
        for (int ni = 0; ni < 5; ++ni)
            bf2r[ks][ni] = *(const s16x8*)(sB + ks * 2560 + (ni * 16 + lm) * 32 + lq * 8);
    f32x4 acc[2][5] = {};
#pragma unroll
    for (int i = 0; i < 2; ++i) {
        const int rowt = (w * 2 + i) * 16 + lm;
#pragma unroll
        for (int ks = 0; ks < 2; ++ks) {
            s16x8 a = *(const s16x8*)(sA + ks * 4096 + rowt * 32 + lq * 8);
#pragma unroll
            for (int ni = 0; ni < 5; ++ni)
                acc[i][ni] = __builtin_amdgcn_mfma_f32_16x16x32_bf16(a, bf2r[ks][ni], acc[i][ni], 0, 0, 0);
        }
    }
#pragma unroll
    for (int i = 0; i < 2; ++i) {
#pragma unroll
        for (int r = 0; r < 4; ++r) {
            const int row = (w * 2 + i) * 16 + lq * 4 + r;
            float den = __shfl(acc[i][4][r], l & 48, 64);
            float rd = 1.f / den;
            const size_t ob = (size_t)(b * 4096 + n0 + row) * 1024 + h * 64 + lm;
            attn[ob]      = f2bf(acc[i][0][r] * rd);
            attn[ob + 16] = f2bf(acc[i][1][r] * rd);
            attn[ob + 32] = f2bf(acc[i][2][r] * rd);
            attn[ob + 48] = f2bf(acc[i][3][r] * rd);
        }
    }
}

// ---------- LayerNorm (D=1024) ----------
__device__ __forceinline__ float block_sum256(float v, float* sbuf, int tid) {
    v = wave_sum(v);
    __syncthreads();
    if ((tid & 63) == 0) sbuf[tid >> 6] = v;
    __syncthreads();
    return sbuf[0] + sbuf[1] + sbuf[2] + sbuf[3];
}

template <int WF32, int WBF16>
__global__ __launch_bounds__(256) void ln_kernel(const float* src, const float* g, const float* b,
                                                 float* dstf, unsigned short* dstb) {
    __shared__ float sbuf[4];
    const int t = blockIdx.x, tid = threadIdx.x;
    float4 v = ((const float4*)(src + (size_t)t * 1024))[tid];
    float mu = block_sum256(v.x + v.y + v.z + v.w, sbuf, tid) * (1.f / 1024.f);
    float dx = v.x - mu, dy = v.y - mu, dz = v.z - mu, dw = v.w - mu;
    float var = block_sum256(dx * dx + dy * dy + dz * dz + dw * dw, sbuf, tid) * (1.f / 1024.f);
    float r = rsqrtf(var + 1e-6f);
    float4 gv = ((const float4*)g)[tid];
    float4 bv = ((const float4*)b)[tid];
    float4 o;
    o.x = dx * r * gv.x + bv.x; o.y = dy * r * gv.y + bv.y;
    o.z = dz * r * gv.z + bv.z; o.w = dw * r * gv.w + bv.w;
    if (WF32) ((float4*)(dstf + (size_t)t * 1024))[tid] = o;
    if (WBF16) {
        ushort4 u; u.x = f2bf(o.x); u.y = f2bf(o.y); u.z = f2bf(o.z); u.w = f2bf(o.w);
        ((ushort4*)(dstb + (size_t)t * 1024))[tid] = u;
    }
}

// ---------- launcher ----------
extern "C" void kernel_launch(void* const* d_in, const int* in_sizes, int n_in,
                              void* d_out, int out_size, void* d_ws, size_t ws_size,
                              hipStream_t stream) {
    (void)in_sizes; (void)n_in; (void)out_size; (void)ws_size;
    const float* x    = (const float*)d_in[0];
    const float* Wq   = (const float*)d_in[1];
    const float* Wk   = (const float*)d_in[2];
    const float* Wv   = (const float*)d_in[3];
    const float* Wo   = (const float*)d_in[4];
    const float* proj = (const float*)d_in[5];
    const float* W1   = (const float*)d_in[6];
    const float* b1   = (const float*)d_in[7];
    const float* W2   = (const float*)d_in[8];
    const float* b2   = (const float*)d_in[9];
    const float* g1   = (const float*)d_in[10];
    const float* lb1  = (const float*)d_in[11];
    const float* g2   = (const float*)d_in[12];
    const float* lb2  = (const float*)d_in[13];

    char* ws = (char*)d_ws;
    size_t off = 0;
    auto alloc = [&](size_t bytes) { char* p = ws + off; off += (bytes + 255) & ~(size_t)255; return p; };
    unsigned short* WqkvT = (unsigned short*)alloc((size_t)3072 * 1024 * 2);
    unsigned short* WoT   = (unsigned short*)alloc((size_t)1024 * 1024 * 2);
    unsigned short* W1T   = (unsigned short*)alloc((size_t)4096 * 1024 * 2);
    unsigned short* W2T   = (unsigned short*)alloc((size_t)1024 * 4096 * 2);
    unsigned short* xb    = (unsigned short*)alloc((size_t)16384 * 1024 * 2);  // later: attn
    unsigned short* qkvb  = (unsigned short*)alloc((size_t)16384 * 3072 * 2);  // later: out1b + h(lo)
    unsigned short* qf    = (unsigned short*)alloc((size_t)16384 * 1024 * 2);  // later: h(mid)
    unsigned short* vT    = (unsigned short*)alloc((size_t)16384 * 1024 * 2);  // later: h(hi)
    float* kv    = (float*)alloc((size_t)64 * 64 * 64 * 4);
    float* ksum  = (float*)alloc((size_t)64 * 64 * 4);
    float* diagk = (float*)alloc((size_t)16384 * 16 * 4);
    float* bmax  = (float*)alloc((size_t)16384 * 4);
    float* mx    = (float*)alloc(256);

    unsigned short* attnb = xb;
    unsigned short* out1b = qkvb;                                   // 32 MB
    unsigned short* h     = qkvb + (size_t)16384 * 1024;            // 128 MB (qkvb hi + qf + vT)
    float* kdash = (float*)d_out;               // d_out doubles as fp32 scratch
    float* preLN = (float*)d_out;

    transpose_all<<<12288, dim3(32, 8), 0, stream>>>(Wq, Wk, Wv, Wo, W1, W2,
                                                     WqkvT, WoT, W1T, W2T);
    cvt_bf16<<<16384, 256, 0, stream>>>((const float4*)x, (ushort4*)xb);

    // QKV: [16384,1024] x [1024,3072]; Q,K -> qkvb (bf16), V -> vT (transposed)
    gemm_bt<EP_QKV><<<dim3(24, 128), 256, 0, stream>>>(xb, 1024, WqkvT, 1024, 1024, 3072,
                                                       nullptr, qkvb, nullptr, nullptr, nullptr, vT);
    feat_mfma<<<2048, 256, 0, stream>>>(qkvb, proj, qf, kdash, diagk, bmax);
    max_reduce<<<1, 256, 0, stream>>>(bmax, mx);
    hipMemsetAsync(kv, 0, (size_t)64 * 64 * 64 * 4 + (size_t)64 * 64 * 4, stream);
    kv_fused<<<dim3(64, 4), 256, 0, stream>>>(kdash, diagk, mx, vT, kv, ksum);
    attn_mfma<<<dim3(64, 32), 256, 0, stream>>>(qf, kv, ksum, attnb);
    // attn @ Wo + x -> preLN1 (in d_out)
    gemm_bt<EP_ADDF32><<<dim3(8, 128), 256, 0, stream>>>(attnb, 1024, WoT, 1024, 1024, 1024,
                                                         preLN, nullptr, nullptr, x, nullptr, nullptr);
    ln_kernel<0, 1><<<16384, 256, 0, stream>>>(preLN, g1, lb1, nullptr, out1b);
    // FFN full-DFF: h = elu(out1b @ W1 + b1)  [16384,4096]
    gemm_bt<EP_BIAS_ELU_BF16><<<dim3(32, 128), 256, 0, stream>>>(out1b, 1024, W1T, 1024, 1024, 4096,
                                                                 nullptr, h, b1, nullptr, nullptr, nullptr);
    // preLN2 = h @ W2 + b2 + out1  (K=4096)
    gemm_bt<EP_BIAS_ADDBF16><<<dim3(8, 128), 256, 0, stream>>>(h, 4096, W2T, 4096, 4096, 1024,
                                                               preLN, nullptr, b2, nullptr, out1b, nullptr);
    ln_kernel<1, 0><<<16384, 256, 0, stream>>>(preLN, g2, lb2, (float*)d_out, nullptr);
}

// Round 7
// 803.565 us; speedup vs baseline: 1.2646x; 1.0614x over previous
//
#include <hip/hip_runtime.h>
#include <math.h>

// ---------- types / helpers ----------
typedef __attribute__((ext_vector_type(8))) short s16x8;
typedef __attribute__((ext_vector_type(4))) float f32x4;

__device__ __forceinline__ float bf2f(unsigned short u) {
    union { unsigned int i; float f; } c; c.i = ((unsigned int)u) << 16; return c.f;
}
__device__ __forceinline__ unsigned short f2bf(float f) {
    union { float f; unsigned int i; } c; c.f = f;
    unsigned int r = c.i + 0x7fffu + ((c.i >> 16) & 1u);
    return (unsigned short)(r >> 16);
}
__device__ __forceinline__ float wave_sum(float v) {
#pragma unroll
    for (int o = 32; o; o >>= 1) v += __shfl_xor(v, o, 64);
    return v;
}
__device__ __forceinline__ float wave_max(float v) {
#pragma unroll
    for (int o = 32; o; o >>= 1) v = fmaxf(v, __shfl_xor(v, o, 64));
    return v;
}
__device__ __forceinline__ void async_load16(const void* g, void* l) {
    __builtin_amdgcn_global_load_lds(
        (const __attribute__((address_space(1))) unsigned int*)g,
        (__attribute__((address_space(3))) unsigned int*)l, 16, 0, 0);
}

// ---------- bf16 GEMM: C[M,N] = A[M,K] * BT[N,K]^T, 128x128 tile, BK=64 ----------
// r1-proven structure with ONE change: K-step 32 -> 64 (halves barrier+drain count;
// m132's BK=128 regression was occupancy-driven; 32KB LDS here keeps cap at 5 blk/CU).
// LDS [128 rows][64 k] with 16B-slot XOR swizzle: slot(r,s) holds source slot s^(r&7)
// (pre-swizzled per-lane GLOBAL source + swizzled ds_read; gload_lds dest lane-linear,
// rule-21 compliant). Bank math: 8 slots x 8 lanes/slot = 2/bank = b128 minimum.
enum { EP_BF16 = 0, EP_ADDF32 = 1, EP_BIAS_ELU_BF16 = 2, EP_QKV = 4, EP_BIAS_ADDBF16 = 5 };

template <int EP>
__global__ __launch_bounds__(256, 2) void gemm_bt(
    const unsigned short* __restrict__ A, int lda,
    const unsigned short* __restrict__ BT, int ldb,
    int K, int ldc,
    float* Cf, unsigned short* Cb,
    const float* __restrict__ bias, const float* addsrc,
    const unsigned short* __restrict__ addb,
    unsigned short* vtout)
{
    __shared__ __align__(16) unsigned short sA[128 * 64];
    __shared__ __align__(16) unsigned short sB[128 * 64];
    const int tid = threadIdx.x;
    const int w = tid >> 6, l = tid & 63;
    const int wm = w & 1, wn = w >> 1;

    // XCD-chunked bijective swizzle (nwg % 8 == 0 for all our grids)
    unsigned int i = blockIdx.y * gridDim.x + blockIdx.x;
    const unsigned int chunk = (gridDim.x * gridDim.y) >> 3;
    i = (i & 7u) * chunk + (i >> 3);
    const int tileX = i % gridDim.x, tileY = i / gridDim.x;
    const int rowBase = tileY * 128, colBase = tileX * 128;

    f32x4 acc[4][4] = {};

    // staging: wave w owns rows [w*32, w*32+32); unit j covers 8 rows.
    // lane l -> row w*32 + j*8 + (l>>3), dest 16B-slot l&7 (lane-linear),
    // source 16B-slot (l&7)^(l>>3)  [row&7 == l>>3].
    const int lr = l >> 3;
    const int xs = (l & 7) ^ lr;
    const unsigned short* gA = A + (size_t)(rowBase + w * 32 + lr) * lda + xs * 8;
    const unsigned short* gB = BT + (size_t)(colBase + w * 32 + lr) * ldb + xs * 8;
    unsigned short* lA = sA + (w * 32) * 64;
    unsigned short* lB = sB + (w * 32) * 64;

    const int lm = l & 15, lq = l >> 4;
    const int lm7 = lm & 7;

    for (int k0 = 0; k0 < K; k0 += 64) {
        __syncthreads();
#pragma unroll
        for (int j = 0; j < 4; ++j) {
            async_load16(gA + (size_t)(j * 8) * lda + k0, lA + j * 512);
            async_load16(gB + (size_t)(j * 8) * ldb + k0, lB + j * 512);
        }
        __syncthreads();
#pragma unroll
        for (int kk = 0; kk < 2; ++kk) {
            const int sl = (((kk << 2) + lq) ^ lm7) * 8;
            s16x8 af[4], bfr[4];
#pragma unroll
            for (int mi = 0; mi < 4; ++mi)
                af[mi] = *(const s16x8*)(sA + (wm * 64 + mi * 16 + lm) * 64 + sl);
#pragma unroll
            for (int ni = 0; ni < 4; ++ni)
                bfr[ni] = *(const s16x8*)(sB + (wn * 64 + ni * 16 + lm) * 64 + sl);
#pragma unroll
            for (int mi = 0; mi < 4; ++mi)
#pragma unroll
                for (int ni = 0; ni < 4; ++ni)
                    acc[mi][ni] = __builtin_amdgcn_mfma_f32_16x16x32_bf16(
                        af[mi], bfr[ni], acc[mi][ni], 0, 0, 0);
        }
    }

    if (EP == EP_QKV && colBase >= 2048) {
        // write V part transposed: vT[(b*16+h)*64+d][n], 4 consecutive tokens -> ushort4
#pragma unroll
        for (int mi = 0; mi < 4; ++mi) {
            const int row0 = rowBase + wm * 64 + mi * 16 + lq * 4;
            const int bb = row0 >> 12, nn = row0 & 4095;
#pragma unroll
            for (int ni = 0; ni < 4; ++ni) {
                const int c = colBase + wn * 64 + ni * 16 + lm - 2048;
                const int hv = c >> 6, dv = c & 63;
                ushort4 u;
                u.x = f2bf(acc[mi][ni][0]); u.y = f2bf(acc[mi][ni][1]);
                u.z = f2bf(acc[mi][ni][2]); u.w = f2bf(acc[mi][ni][3]);
                *(ushort4*)(vtout + ((size_t)(bb * 16 + hv) * 64 + dv) * 4096 + nn) = u;
            }
        }
    } else {
#pragma unroll
        for (int mi = 0; mi < 4; ++mi) {
            const int r0 = rowBase + wm * 64 + mi * 16 + lq * 4;
#pragma unroll
            for (int ni = 0; ni < 4; ++ni) {
                const int c = colBase + wn * 64 + ni * 16 + lm;
                float bv = 0.f;
                if (EP == EP_BIAS_ELU_BF16 || EP == EP_BIAS_ADDBF16) bv = bias[c];
#pragma unroll
                for (int r = 0; r < 4; ++r) {
                    const size_t idx = (size_t)(r0 + r) * ldc + c;
                    float v = acc[mi][ni][r] + bv;
                    if (EP == EP_ADDF32) v += addsrc[idx];
                    if (EP == EP_BIAS_ADDBF16) v += bf2f(addb[idx]);
                    if (EP == EP_BIAS_ELU_BF16) v = v > 0.f ? v : (expf(v) - 1.f);
                    if (EP == EP_BF16 || EP == EP_BIAS_ELU_BF16 || EP == EP_QKV) Cb[idx] = f2bf(v);
                    else Cf[idx] = v;
                }
            }
        }
    }
}

// ---------- all weight transposes + f32->bf16 in one dispatch ----------
__global__ __launch_bounds__(256) void transpose_all(
    const float* __restrict__ Wq, const float* __restrict__ Wk,
    const float* __restrict__ Wv, const float* __restrict__ Wo,
    const float* __restrict__ W1, const float* __restrict__ W2,
    unsigned short* WqkvT, unsigned short* WoT,
    unsigned short* W1T, unsigned short* W2T)
{
    __shared__ float t[32][33];
    const int bid = blockIdx.x;
    const float* in;
    unsigned short* out;
    int R, C, tx32, ty32;
    if (bid < 4096) {
        const int job = bid >> 10, tile = bid & 1023;
        ty32 = tile >> 5; tx32 = tile & 31;
        R = 1024; C = 1024;
        if (job == 0)      { in = Wq; out = WqkvT; }
        else if (job == 1) { in = Wk; out = WqkvT + 1024 * 1024; }
        else if (job == 2) { in = Wv; out = WqkvT + 2 * 1024 * 1024; }
        else               { in = Wo; out = WoT; }
    } else if (bid < 8192) {
        const int tile = bid - 4096;           // W1 [1024,4096]: 128 x-tiles, 32 y-tiles
        tx32 = tile & 127; ty32 = tile >> 7;
        R = 1024; C = 4096; in = W1; out = W1T;
    } else {
        const int tile = bid - 8192;           // W2 [4096,1024]: 32 x-tiles, 128 y-tiles
        tx32 = tile & 31; ty32 = tile >> 5;
        R = 4096; C = 1024; in = W2; out = W2T;
    }
    const int c0 = tx32 * 32, r0 = ty32 * 32;
    const int tx = threadIdx.x, ty = threadIdx.y;
#pragma unroll
    for (int j = 0; j < 4; ++j)
        t[ty + j * 8][tx] = in[(size_t)(r0 + ty + j * 8) * C + c0 + tx];
    __syncthreads();
#pragma unroll
    for (int j = 0; j < 4; ++j) {
        int cc = ty + j * 8;
        out[(size_t)(c0 + cc) * R + r0 + tx] = f2bf(t[tx][cc]);
    }
}

__global__ __launch_bounds__(256) void cvt_bf16(const float4* in, ushort4* out) {
    size_t i = (size_t)blockIdx.x * 256 + threadIdx.x;
    float4 v = in[i];
    ushort4 o; o.x = f2bf(v.x); o.y = f2bf(v.y); o.z = f2bf(v.z); o.w = f2bf(v.w);
    out[i] = o;
}

// ---------- FAVOR+ features via MFMA ----------
__global__ __launch_bounds__(256, 2) void feat_mfma(
    const unsigned short* __restrict__ qkvb, const float* __restrict__ proj,
    unsigned short* __restrict__ qf, float* __restrict__ kdash,
    float* __restrict__ diagk, float* __restrict__ bmax)
{
    __shared__ __align__(16) unsigned short sQ[8192];  // [2 ks][128 rows][32 k]
    __shared__ __align__(16) unsigned short sK[8192];
    __shared__ __align__(16) unsigned short sP[4096];  // proj [2 ks][64 m][32 k]
    __shared__ float sdq[128], sdk[128];
    __shared__ float swm[4];
    const int tid = threadIdx.x, w = tid >> 6, l = tid & 63;
    const int t0 = blockIdx.x * 8;
    const int lm = l & 15, lq = l >> 4;

#pragma unroll
    for (int j = 0; j < 4; ++j) {
        const int lt = 2 * w + (j & 1), ks = j >> 1;
        const size_t g = (size_t)(t0 + lt) * 3072 + (l >> 2) * 64 + ks * 32 + (l & 3) * 8;
        async_load16(qkvb + g, sQ + ks * 4096 + lt * 512);
        async_load16(qkvb + g + 1024, sK + ks * 4096 + lt * 512);
    }
    for (int i = tid; i < 4096; i += 256) {
        int m = i >> 6, d = i & 63;
        sP[(d >> 5) * 2048 + m * 32 + (d & 31)] = f2bf(proj[i]);
    }
    __syncthreads();

    {
        int r = tid & 127;
        const unsigned short* src = (tid < 128) ? sQ : sK;
        float s = 0.f;
#pragma unroll
        for (int ks = 0; ks < 2; ++ks) {
            const s16x8* p = (const s16x8*)(src + ks * 4096 + r * 32);
#pragma unroll
            for (int c = 0; c < 4; ++c) {
                s16x8 v = p[c];
#pragma unroll
                for (int e = 0; e < 8; ++e) { float f = bf2f((unsigned short)v[e]); s += f * f; }
            }
        }
        if (tid < 128) sdq[r] = s * 0.0625f; else sdk[r] = s * 0.0625f;
    }
    __syncthreads();

    s16x8 pf2[2][4];
#pragma unroll
    for (int ks = 0; ks < 2; ++ks)
#pragma unroll
        for (int ni = 0; ni < 4; ++ni)
            pf2[ks][ni] = *(const s16x8*)(sP + ks * 2048 + (ni * 16 + lm) * 32 + lq * 8);
    f32x4 qa[2][4] = {}, ka[2][4] = {};
#pragma unroll
    for (int i = 0; i < 2; ++i) {
        const int rowt = (w * 2 + i) * 16 + lm;
#pragma unroll
        for (int ks = 0; ks < 2; ++ks) {
            s16x8 aq = *(const s16x8*)(sQ + ks * 4096 + rowt * 32 + lq * 8);
            s16x8 ak = *(const s16x8*)(sK + ks * 4096 + rowt * 32 + lq * 8);
#pragma unroll
            for (int ni = 0; ni < 4; ++ni) {
                qa[i][ni] = __builtin_amdgcn_mfma_f32_16x16x32_bf16(aq, pf2[ks][ni], qa[i][ni], 0, 0, 0);
                ka[i][ni] = __builtin_amdgcn_mfma_f32_16x16x32_bf16(ak, pf2[ks][ni], ka[i][ni], 0, 0, 0);
            }
        }
    }

    const float dn = 0.35355339059327373f;
    float kmax = -3.0e38f;
#pragma unroll
    for (int i = 0; i < 2; ++i) {
#pragma unroll
        for (int r = 0; r < 4; ++r) {
            const int row = (w * 2 + i) * 16 + lq * 4 + r;
            float q0 = qa[i][0][r] * dn, q1 = qa[i][1][r] * dn;
            float q2 = qa[i][2][r] * dn, q3 = qa[i][3][r] * dn;
            float mq = fmaxf(fmaxf(q0, q1), fmaxf(q2, q3));
#pragma unroll
            for (int o = 1; o < 16; o <<= 1) mq = fmaxf(mq, __shfl_xor(mq, o, 64));
            const float dg = sdq[row];
            const size_t ob = (size_t)t0 * 1024 + (size_t)row * 64 + lm;
            qf[ob]      = f2bf(0.125f * (expf(q0 - dg - mq) + 1e-6f));
            qf[ob + 16] = f2bf(0.125f * (expf(q1 - dg - mq) + 1e-6f));
            qf[ob + 32] = f2bf(0.125f * (expf(q2 - dg - mq) + 1e-6f));
            qf[ob + 48] = f2bf(0.125f * (expf(q3 - dg - mq) + 1e-6f));
#pragma unroll
            for (int ni = 0; ni < 4; ++ni) {
                float kd = ka[i][ni][r] * dn;
                kdash[ob + ni * 16] = kd;
                kmax = fmaxf(kmax, kd);
            }
        }
    }
    kmax = wave_max(kmax);
    if (l == 0) swm[w] = kmax;
    __syncthreads();
    if (tid < 128) diagk[t0 * 16 + tid] = sdk[tid];
    if (tid == 0) bmax[blockIdx.x] = fmaxf(fmaxf(swm[0], swm[1]), fmaxf(swm[2], swm[3]));
}

__global__ __launch_bounds__(256) void max_reduce(const float* bm, float* mx) {
    const int tid = threadIdx.x;
    float m = -3.0e38f;
    for (int i = tid; i < 2048; i += 256) m = fmaxf(m, bm[i]);
    m = wave_max(m);
    __shared__ float s[4];
    if ((tid & 63) == 0) s[tid >> 6] = m;
    __syncthreads();
    if (tid == 0) mx[0] = fmaxf(fmaxf(s[0], s[1]), fmaxf(s[2], s[3]));
}

// ---------- fused kf + kv/ksum via MFMA ----------
__global__ __launch_bounds__(256, 2) void kv_fused(
    const float* __restrict__ kdash, const float* __restrict__ diagk,
    const float* __restrict__ mx, const unsigned short* __restrict__ vT,
    float* kv, float* ksum)
{
    __shared__ __align__(16) unsigned short sKF[64 * 72];
    __shared__ __align__(16) unsigned short sV[64 * 72];
    __shared__ float sDiag[1024];
    const int tid = threadIdx.x, w = tid >> 6, l = tid & 63;
    const int bh = blockIdx.x, b = bh >> 4, h = bh & 15;
    const int n0 = blockIdx.y * 1024;
    const int lm = l & 15, lq = l >> 4;
    const float mxv = mx[0];

    for (int i = tid; i < 1024; i += 256)
        sDiag[i] = diagk[(size_t)(b * 4096 + n0 + i) * 16 + h] + mxv;

    s16x8 onesf;
    {
        short ov = (lm == 0) ? (short)0x3F80 : (short)0;
#pragma unroll
        for (int j = 0; j < 8; ++j) onesf[j] = ov;
    }
    f32x4 acc[4] = {};
    f32x4 accS = {};
    __syncthreads();

    for (int c0 = 0; c0 < 1024; c0 += 64) {
        __syncthreads();
        {
            const int n = c0 + l;
            const size_t krow = ((size_t)(b * 4096 + n0 + n)) * 1024 + h * 64 + w * 16;
            const float4* kp = (const float4*)(kdash + krow);
            float4 k0 = kp[0], k1 = kp[1], k2 = kp[2], k3 = kp[3];
            const float dg = sDiag[n];
            float vv[16] = {k0.x, k0.y, k0.z, k0.w, k1.x, k1.y, k1.z, k1.w,
                            k2.x, k2.y, k2.z, k2.w, k3.x, k3.y, k3.z, k3.w};
            unsigned short* dst = sKF + (w * 16) * 72 + l;
#pragma unroll
            for (int e = 0; e < 16; ++e)
                dst[e * 72] = f2bf(0.125f * (expf(vv[e] - dg) + 1e-6f));
        }
        {
            const int d = tid >> 2, nq = tid & 3;
            const uint4* vp = (const uint4*)(vT + ((size_t)bh * 64 + d) * 4096 + n0 + c0 + nq * 16);
            uint4 v0 = vp[0], v1 = vp[1];
            uint4* ldst = (uint4*)(sV + d * 72 + nq * 16);
            ldst[0] = v0; ldst[1] = v1;
        }
        __syncthreads();
#pragma unroll
        for (int ks = 0; ks < 2; ++ks) {
            s16x8 a = *(const s16x8*)(sKF + (w * 16 + lm) * 72 + ks * 32 + lq * 8);
            accS = __builtin_amdgcn_mfma_f32_16x16x32_bf16(a, onesf, accS, 0, 0, 0);
#pragma unroll
            for (int ni = 0; ni < 4; ++ni) {
                s16x8 bf = *(const s16x8*)(sV + (ni * 16 + lm) * 72 + ks * 32 + lq * 8);
                acc[ni] = __builtin_amdgcn_mfma_f32_16x16x32_bf16(a, bf, acc[ni], 0, 0, 0);
            }
        }
    }

    const size_t kvbase = (size_t)bh * 4096;
#pragma unroll
    for (int ni = 0; ni < 4; ++ni)
#pragma unroll
        for (int r = 0; r < 4; ++r)
            atomicAdd(kv + kvbase + (size_t)(w * 16 + lq * 4 + r) * 64 + ni * 16 + lm, acc[ni][r]);
    if (lm == 0)
#pragma unroll
        for (int r = 0; r < 4; ++r)
            atomicAdd(ksum + bh * 64 + w * 16 + lq * 4 + r, accS[r]);
}

// ---------- attention combine via MFMA, den folded as output column 64 ----------
__global__ __launch_bounds__(256, 2) void attn_mfma(const unsigned short* __restrict__ qf,
                                                    const float* __restrict__ kv,
                                                    const float* __restrict__ ksum,
                                                    unsigned short* __restrict__ attn) {
    __shared__ __align__(16) unsigned short sA[8192];  // [2 ks][128 rows][32 m]
    __shared__ __align__(16) unsigned short sB[5120];  // [2 ks][80 cols][32 m]; col64=ksum
    const int tid = threadIdx.x, w = tid >> 6, l = tid & 63;
    const int bh = blockIdx.x, b = bh >> 4, h = bh & 15;
    const int n0 = blockIdx.y * 128;
    const int lm = l & 15, lq = l >> 4;

#pragma unroll
    for (int j = 0; j < 4; ++j) {
        const int r0 = w * 32 + (j & 1) * 16, ks = j >> 1;
        const size_t g = (size_t)(b * 4096 + n0 + r0 + (l >> 2)) * 1024 + h * 64 + ks * 32 + (l & 3) * 8;
        async_load16(qf + g, sA + ks * 4096 + r0 * 32);
    }
    for (int i = tid; i < 5120; i += 256) sB[i] = 0;
    __syncthreads();
    for (int i = tid; i < 4096; i += 256) {
        int m = i >> 6, d = i & 63;
        sB[(m >> 5) * 2560 + d * 32 + (m & 31)] = f2bf(kv[(size_t)bh * 4096 + i]);
    }
    if (tid < 64) {
        int m = tid;
        sB[(m >> 5) * 2560 + 64 * 32 + (m & 31)] = f2bf(ksum[bh * 64 + m]);
    }
    __syncthreads();

    s16x8 bf2r[2][5];
#pragma unroll
    for (int ks = 0; ks < 2; ++ks)
#pragma unroll
        for (int ni = 0; ni < 5; ++ni)
            bf2r[ks][ni] = *(const s16x8*)(sB + ks * 2560 + (ni * 16 + lm) * 32 + lq * 8);
    f32x4 acc[2][5] = {};
#pragma unroll
    for (int i = 0; i < 2; ++i) {
        const int rowt = (w * 2 + i) * 16 + lm;
#pragma unroll
        for (int ks = 0; ks < 2; ++ks) {
            s16x8 a = *(const s16x8*)(sA + ks * 4096 + rowt * 32 + lq * 8);
#pragma unroll
            for (int ni = 0; ni < 5; ++ni)
                acc[i][ni] = __builtin_amdgcn_mfma_f32_16x16x32_bf16(a, bf2r[ks][ni], acc[i][ni], 0, 0, 0);
        }
    }
#pragma unroll
    for (int i = 0; i < 2; ++i) {
#pragma unroll
        for (int r = 0; r < 4; ++r) {
            const int row = (w * 2 + i) * 16 + lq * 4 + r;
            float den = __shfl(acc[i][4][r], l & 48, 64);
            float rd = 1.f / den;
            const size_t ob = (size_t)(b * 4096 + n0 + row) * 1024 + h * 64 + lm;
            attn[ob]      = f2bf(acc[i][0][r] * rd);
            attn[ob + 16] = f2bf(acc[i][1][r] * rd);
            attn[ob + 32] = f2bf(acc[i][2][r] * rd);
            attn[ob + 48] = f2bf(acc[i][3][r] * rd);
        }
    }
}

// ---------- LayerNorm (D=1024) ----------
__device__ __forceinline__ float block_sum256(float v, float* sbuf, int tid) {
    v = wave_sum(v);
    __syncthreads();
    if ((tid & 63) == 0) sbuf[tid >> 6] = v;
    __syncthreads();
    return sbuf[0] + sbuf[1] + sbuf[2] + sbuf[3];
}

template <int WF32, int WBF16>
__global__ __launch_bounds__(256) void ln_kernel(const float* src, const float* g, const float* b,
                                                 float* dstf, unsigned short* dstb) {
    __shared__ float sbuf[4];
    const int t = blockIdx.x, tid = threadIdx.x;
    float4 v = ((const float4*)(src + (size_t)t * 1024))[tid];
    float mu = block_sum256(v.x + v.y + v.z + v.w, sbuf, tid) * (1.f / 1024.f);
    float dx = v.x - mu, dy = v.y - mu, dz = v.z - mu, dw = v.w - mu;
    float var = block_sum256(dx * dx + dy * dy + dz * dz + dw * dw, sbuf, tid) * (1.f / 1024.f);
    float r = rsqrtf(var + 1e-6f);
    float4 gv = ((const float4*)g)[tid];
    float4 bv = ((const float4*)b)[tid];
    float4 o;
    o.x = dx * r * gv.x + bv.x; o.y = dy * r * gv.y + bv.y;
    o.z = dz * r * gv.z + bv.z; o.w = dw * r * gv.w + bv.w;
    if (WF32) ((float4*)(dstf + (size_t)t * 1024))[tid] = o;
    if (WBF16) {
        ushort4 u; u.x = f2bf(o.x); u.y = f2bf(o.y); u.z = f2bf(o.z); u.w = f2bf(o.w);
        ((ushort4*)(dstb + (size_t)t * 1024))[tid] = u;
    }
}

// ---------- launcher ----------
extern "C" void kernel_launch(void* const* d_in, const int* in_sizes, int n_in,
                              void* d_out, int out_size, void* d_ws, size_t ws_size,
                              hipStream_t stream) {
    (void)in_sizes; (void)n_in; (void)out_size; (void)ws_size;
    const float* x    = (const float*)d_in[0];
    const float* Wq   = (const float*)d_in[1];
    const float* Wk   = (const float*)d_in[2];
    const float* Wv   = (const float*)d_in[3];
    const float* Wo   = (const float*)d_in[4];
    const float* proj = (const float*)d_in[5];
    const float* W1   = (const float*)d_in[6];
    const float* b1   = (const float*)d_in[7];
    const float* W2   = (const float*)d_in[8];
    const float* b2   = (const float*)d_in[9];
    const float* g1   = (const float*)d_in[10];
    const float* lb1  = (const float*)d_in[11];
    const float* g2   = (const float*)d_in[12];
    const float* lb2  = (const float*)d_in[13];

    char* ws = (char*)d_ws;
    size_t off = 0;
    auto alloc = [&](size_t bytes) { char* p = ws + off; off += (bytes + 255) & ~(size_t)255; return p; };
    unsigned short* WqkvT = (unsigned short*)alloc((size_t)3072 * 1024 * 2);
    unsigned short* WoT   = (unsigned short*)alloc((size_t)1024 * 1024 * 2);
    unsigned short* W1T   = (unsigned short*)alloc((size_t)4096 * 1024 * 2);
    unsigned short* W2T   = (unsigned short*)alloc((size_t)1024 * 4096 * 2);
    unsigned short* xb    = (unsigned short*)alloc((size_t)16384 * 1024 * 2);  // later: attn
    unsigned short* qkvb  = (unsigned short*)alloc((size_t)16384 * 3072 * 2);  // later: out1b + h(lo)
    unsigned short* qf    = (unsigned short*)alloc((size_t)16384 * 1024 * 2);  // later: h(mid)
    unsigned short* vT    = (unsigned short*)alloc((size_t)16384 * 1024 * 2);  // later: h(hi)
    float* kv    = (float*)alloc((size_t)64 * 64 * 64 * 4);
    float* ksum  = (float*)alloc((size_t)64 * 64 * 4);
    float* diagk = (float*)alloc((size_t)16384 * 16 * 4);
    float* bmax  = (float*)alloc((size_t)16384 * 4);
    float* mx    = (float*)alloc(256);

    unsigned short* attnb = xb;
    unsigned short* out1b = qkvb;                                   // 32 MB
    unsigned short* h     = qkvb + (size_t)16384 * 1024;            // 128 MB (qkvb hi + qf + vT)
    float* kdash = (float*)d_out;               // d_out doubles as fp32 scratch
    float* preLN = (float*)d_out;

    transpose_all<<<12288, dim3(32, 8), 0, stream>>>(Wq, Wk, Wv, Wo, W1, W2,
                                                     WqkvT, WoT, W1T, W2T);
    cvt_bf16<<<16384, 256, 0, stream>>>((const float4*)x, (ushort4*)xb);

    // QKV: [16384,1024] x [1024,3072]; Q,K -> qkvb (bf16), V -> vT (transposed)
    gemm_bt<EP_QKV><<<dim3(24, 128), 256, 0, stream>>>(xb, 1024, WqkvT, 1024, 1024, 3072,
                                                       nullptr, qkvb, nullptr, nullptr, nullptr, vT);
    feat_mfma<<<2048, 256, 0, stream>>>(qkvb, proj, qf, kdash, diagk, bmax);
    max_reduce<<<1, 256, 0, stream>>>(bmax, mx);
    hipMemsetAsync(kv, 0, (size_t)64 * 64 * 64 * 4 + (size_t)64 * 64 * 4, stream);
    kv_fused<<<dim3(64, 4), 256, 0, stream>>>(kdash, diagk, mx, vT, kv, ksum);
    attn_mfma<<<dim3(64, 32), 256, 0, stream>>>(qf, kv, ksum, attnb);
    // attn @ Wo + x -> preLN1 (in d_out)
    gemm_bt<EP_ADDF32><<<dim3(8, 128), 256, 0, stream>>>(attnb, 1024, WoT, 1024, 1024, 1024,
                                                         preLN, nullptr, nullptr, x, nullptr, nullptr);
    ln_kernel<0, 1><<<16384, 256, 0, stream>>>(preLN, g1, lb1, nullptr, out1b);
    // FFN full-DFF: h = elu(out1b @ W1 + b1)  [16384,4096]
    gemm_bt<EP_BIAS_ELU_BF16><<<dim3(32, 128), 256, 0, stream>>>(out1b, 1024, W1T, 1024, 1024, 4096,
                                                                 nullptr, h, b1, nullptr, nullptr, nullptr);
    // preLN2 = h @ W2 + b2 + out1  (K=4096)
    gemm_bt<EP_BIAS_ADDBF16><<<dim3(8, 128), 256, 0, stream>>>(h, 4096, W2T, 4096, 4096, 1024,
                                                               preLN, nullptr, b2, nullptr, out1b, nullptr);
    ln_kernel<1, 0><<<16384, 256, 0, stream>>>(preLN, g2, lb2, (float*)d_out, nullptr);
}

// Round 8
// 757.431 us; speedup vs baseline: 1.3417x; 1.0609x over previous
//
#include <hip/hip_runtime.h>
#include <math.h>

// ---------- types / helpers ----------
typedef __attribute__((ext_vector_type(8))) short s16x8;
typedef __attribute__((ext_vector_type(4))) float f32x4;

__device__ __forceinline__ float bf2f(unsigned short u) {
    union { unsigned int i; float f; } c; c.i = ((unsigned int)u) << 16; return c.f;
}
__device__ __forceinline__ unsigned short f2bf(float f) {
    union { float f; unsigned int i; } c; c.f = f;
    unsigned int r = c.i + 0x7fffu + ((c.i >> 16) & 1u);
    return (unsigned short)(r >> 16);
}
__device__ __forceinline__ float wave_sum(float v) {
#pragma unroll
    for (int o = 32; o; o >>= 1) v += __shfl_xor(v, o, 64);
    return v;
}
__device__ __forceinline__ float wave_max(float v) {
#pragma unroll
    for (int o = 32; o; o >>= 1) v = fmaxf(v, __shfl_xor(v, o, 64));
    return v;
}
__device__ __forceinline__ void async_load16(const void* g, void* l) {
    __builtin_amdgcn_global_load_lds(
        (const __attribute__((address_space(1))) unsigned int*)g,
        (__attribute__((address_space(3))) unsigned int*)l, 16, 0, 0);
}

// ---------- bf16 GEMM: C[M,N] = A[M,K] * BT[N,K]^T, 128x128 tile, BK=64 ----------
// r7-proven structure (803.6 us total; FFN1 162us/848TF, bank-conflict 0).
// LDS [128 rows][64 k] with 16B-slot XOR swizzle (rule-21 compliant: pre-swizzled
// per-lane global source + swizzled ds_read; gload_lds dest lane-linear).
// EP_ADDF32B (new): add f32 residual, emit bf16 (preLN1 traffic halved).
enum { EP_BF16 = 0, EP_ADDF32 = 1, EP_BIAS_ELU_BF16 = 2, EP_QKV = 4, EP_BIAS_ADDBF16 = 5,
       EP_ADDF32B = 6 };

template <int EP>
__global__ __launch_bounds__(256, 2) void gemm_bt(
    const unsigned short* __restrict__ A, int lda,
    const unsigned short* __restrict__ BT, int ldb,
    int K, int ldc,
    float* Cf, unsigned short* Cb,
    const float* __restrict__ bias, const float* addsrc,
    const unsigned short* __restrict__ addb,
    unsigned short* vtout)
{
    __shared__ __align__(16) unsigned short sA[128 * 64];
    __shared__ __align__(16) unsigned short sB[128 * 64];
    const int tid = threadIdx.x;
    const int w = tid >> 6, l = tid & 63;
    const int wm = w & 1, wn = w >> 1;

    // XCD-chunked bijective swizzle (nwg % 8 == 0 for all our grids)
    unsigned int i = blockIdx.y * gridDim.x + blockIdx.x;
    const unsigned int chunk = (gridDim.x * gridDim.y) >> 3;
    i = (i & 7u) * chunk + (i >> 3);
    const int tileX = i % gridDim.x, tileY = i / gridDim.x;
    const int rowBase = tileY * 128, colBase = tileX * 128;

    f32x4 acc[4][4] = {};

    // staging: wave w owns rows [w*32, w*32+32); unit j covers 8 rows.
    // lane l -> row w*32 + j*8 + (l>>3), dest 16B-slot l&7 (lane-linear),
    // source 16B-slot (l&7)^(l>>3)  [row&7 == l>>3].
    const int lr = l >> 3;
    const int xs = (l & 7) ^ lr;
    const unsigned short* gA = A + (size_t)(rowBase + w * 32 + lr) * lda + xs * 8;
    const unsigned short* gB = BT + (size_t)(colBase + w * 32 + lr) * ldb + xs * 8;
    unsigned short* lA = sA + (w * 32) * 64;
    unsigned short* lB = sB + (w * 32) * 64;

    const int lm = l & 15, lq = l >> 4;
    const int lm7 = lm & 7;

    for (int k0 = 0; k0 < K; k0 += 64) {
        __syncthreads();
#pragma unroll
        for (int j = 0; j < 4; ++j) {
            async_load16(gA + (size_t)(j * 8) * lda + k0, lA + j * 512);
            async_load16(gB + (size_t)(j * 8) * ldb + k0, lB + j * 512);
        }
        __syncthreads();
#pragma unroll
        for (int kk = 0; kk < 2; ++kk) {
            const int sl = (((kk << 2) + lq) ^ lm7) * 8;
            s16x8 af[4], bfr[4];
#pragma unroll
            for (int mi = 0; mi < 4; ++mi)
                af[mi] = *(const s16x8*)(sA + (wm * 64 + mi * 16 + lm) * 64 + sl);
#pragma unroll
            for (int ni = 0; ni < 4; ++ni)
                bfr[ni] = *(const s16x8*)(sB + (wn * 64 + ni * 16 + lm) * 64 + sl);
#pragma unroll
            for (int mi = 0; mi < 4; ++mi)
#pragma unroll
                for (int ni = 0; ni < 4; ++ni)
                    acc[mi][ni] = __builtin_amdgcn_mfma_f32_16x16x32_bf16(
                        af[mi], bfr[ni], acc[mi][ni], 0, 0, 0);
        }
    }

    if (EP == EP_QKV && colBase >= 2048) {
        // write V part transposed: vT[(b*16+h)*64+d][n], 4 consecutive tokens -> ushort4
#pragma unroll
        for (int mi = 0; mi < 4; ++mi) {
            const int row0 = rowBase + wm * 64 + mi * 16 + lq * 4;
            const int bb = row0 >> 12, nn = row0 & 4095;
#pragma unroll
            for (int ni = 0; ni < 4; ++ni) {
                const int c = colBase + wn * 64 + ni * 16 + lm - 2048;
                const int hv = c >> 6, dv = c & 63;
                ushort4 u;
                u.x = f2bf(acc[mi][ni][0]); u.y = f2bf(acc[mi][ni][1]);
                u.z = f2bf(acc[mi][ni][2]); u.w = f2bf(acc[mi][ni][3]);
                *(ushort4*)(vtout + ((size_t)(bb * 16 + hv) * 64 + dv) * 4096 + nn) = u;
            }
        }
    } else {
#pragma unroll
        for (int mi = 0; mi < 4; ++mi) {
            const int r0 = rowBase + wm * 64 + mi * 16 + lq * 4;
#pragma unroll
            for (int ni = 0; ni < 4; ++ni) {
                const int c = colBase + wn * 64 + ni * 16 + lm;
                float bv = 0.f;
                if (EP == EP_BIAS_ELU_BF16 || EP == EP_BIAS_ADDBF16) bv = bias[c];
#pragma unroll
                for (int r = 0; r < 4; ++r) {
                    const size_t idx = (size_t)(r0 + r) * ldc + c;
                    float v = acc[mi][ni][r] + bv;
                    if (EP == EP_ADDF32 || EP == EP_ADDF32B) v += addsrc[idx];
                    if (EP == EP_BIAS_ADDBF16) v += bf2f(addb[idx]);
                    if (EP == EP_BIAS_ELU_BF16) v = v > 0.f ? v : (expf(v) - 1.f);
                    if (EP == EP_BF16 || EP == EP_BIAS_ELU_BF16 || EP == EP_QKV ||
                        EP == EP_ADDF32B) Cb[idx] = f2bf(v);
                    else Cf[idx] = v;
                }
            }
        }
    }
}

// ---------- all weight transposes + f32->bf16 in one dispatch ----------
__global__ __launch_bounds__(256) void transpose_all(
    const float* __restrict__ Wq, const float* __restrict__ Wk,
    const float* __restrict__ Wv, const float* __restrict__ Wo,
    const float* __restrict__ W1, const float* __restrict__ W2,
    unsigned short* WqkvT, unsigned short* WoT,
    unsigned short* W1T, unsigned short* W2T)
{
    __shared__ float t[32][33];
    const int bid = blockIdx.x;
    const float* in;
    unsigned short* out;
    int R, C, tx32, ty32;
    if (bid < 4096) {
        const int job = bid >> 10, tile = bid & 1023;
        ty32 = tile >> 5; tx32 = tile & 31;
        R = 1024; C = 1024;
        if (job == 0)      { in = Wq; out = WqkvT; }
        else if (job == 1) { in = Wk; out = WqkvT + 1024 * 1024; }
        else if (job == 2) { in = Wv; out = WqkvT + 2 * 1024 * 1024; }
        else               { in = Wo; out = WoT; }
    } else if (bid < 8192) {
        const int tile = bid - 4096;           // W1 [1024,4096]: 128 x-tiles, 32 y-tiles
        tx32 = tile & 127; ty32 = tile >> 7;
        R = 1024; C = 4096; in = W1; out = W1T;
    } else {
        const int tile = bid - 8192;           // W2 [4096,1024]: 32 x-tiles, 128 y-tiles
        tx32 = tile & 31; ty32 = tile >> 5;
        R = 4096; C = 1024; in = W2; out = W2T;
    }
    const int c0 = tx32 * 32, r0 = ty32 * 32;
    const int tx = threadIdx.x, ty = threadIdx.y;
#pragma unroll
    for (int j = 0; j < 4; ++j)
        t[ty + j * 8][tx] = in[(size_t)(r0 + ty + j * 8) * C + c0 + tx];
    __syncthreads();
#pragma unroll
    for (int j = 0; j < 4; ++j) {
        int cc = ty + j * 8;
        out[(size_t)(c0 + cc) * R + r0 + tx] = f2bf(t[tx][cc]);
    }
}

__global__ __launch_bounds__(256) void cvt_bf16(const float4* in, ushort4* out) {
    size_t i = (size_t)blockIdx.x * 256 + threadIdx.x;
    float4 v = in[i];
    ushort4 o; o.x = f2bf(v.x); o.y = f2bf(v.y); o.z = f2bf(v.z); o.w = f2bf(v.w);
    out[i] = o;
}

// ---------- FAVOR+ features via MFMA (kdash now bf16) ----------
__global__ __launch_bounds__(256, 2) void feat_mfma(
    const unsigned short* __restrict__ qkvb, const float* __restrict__ proj,
    unsigned short* __restrict__ qf, unsigned short* __restrict__ kdash,
    float* __restrict__ diagk, float* __restrict__ bmax)
{
    __shared__ __align__(16) unsigned short sQ[8192];  // [2 ks][128 rows][32 k]
    __shared__ __align__(16) unsigned short sK[8192];
    __shared__ __align__(16) unsigned short sP[4096];  // proj [2 ks][64 m][32 k]
    __shared__ float sdq[128], sdk[128];
    __shared__ float swm[4];
    const int tid = threadIdx.x, w = tid >> 6, l = tid & 63;
    const int t0 = blockIdx.x * 8;
    const int lm = l & 15, lq = l >> 4;

#pragma unroll
    for (int j = 0; j < 4; ++j) {
        const int lt = 2 * w + (j & 1), ks = j >> 1;
        const size_t g = (size_t)(t0 + lt) * 3072 + (l >> 2) * 64 + ks * 32 + (l & 3) * 8;
        async_load16(qkvb + g, sQ + ks * 4096 + lt * 512);
        async_load16(qkvb + g + 1024, sK + ks * 4096 + lt * 512);
    }
    for (int i = tid; i < 4096; i += 256) {
        int m = i >> 6, d = i & 63;
        sP[(d >> 5) * 2048 + m * 32 + (d & 31)] = f2bf(proj[i]);
    }
    __syncthreads();

    {
        int r = tid & 127;
        const unsigned short* src = (tid < 128) ? sQ : sK;
        float s = 0.f;
#pragma unroll
        for (int ks = 0; ks < 2; ++ks) {
            const s16x8* p = (const s16x8*)(src + ks * 4096 + r * 32);
#pragma unroll
            for (int c = 0; c < 4; ++c) {
                s16x8 v = p[c];
#pragma unroll
                for (int e = 0; e < 8; ++e) { float f = bf2f((unsigned short)v[e]); s += f * f; }
            }
        }
        if (tid < 128) sdq[r] = s * 0.0625f; else sdk[r] = s * 0.0625f;
    }
    __syncthreads();

    s16x8 pf2[2][4];
#pragma unroll
    for (int ks = 0; ks < 2; ++ks)
#pragma unroll
        for (int ni = 0; ni < 4; ++ni)
            pf2[ks][ni] = *(const s16x8*)(sP + ks * 2048 + (ni * 16 + lm) * 32 + lq * 8);
    f32x4 qa[2][4] = {}, ka[2][4] = {};
#pragma unroll
    for (int i = 0; i < 2; ++i) {
        const int rowt = (w * 2 + i) * 16 + lm;
#pragma unroll
        for (int ks = 0; ks < 2; ++ks) {
            s16x8 aq = *(const s16x8*)(sQ + ks * 4096 + rowt * 32 + lq * 8);
            s16x8 ak = *(const s16x8*)(sK + ks * 4096 + rowt * 32 + lq * 8);
#pragma unroll
            for (int ni = 0; ni < 4; ++ni) {
                qa[i][ni] = __builtin_amdgcn_mfma_f32_16x16x32_bf16(aq, pf2[ks][ni], qa[i][ni], 0, 0, 0);
                ka[i][ni] = __builtin_amdgcn_mfma_f32_16x16x32_bf16(ak, pf2[ks][ni], ka[i][ni], 0, 0, 0);
            }
        }
    }

    const float dn = 0.35355339059327373f;
    float kmax = -3.0e38f;
#pragma unroll
    for (int i = 0; i < 2; ++i) {
#pragma unroll
        for (int r = 0; r < 4; ++r) {
            const int row = (w * 2 + i) * 16 + lq * 4 + r;
            float q0 = qa[i][0][r] * dn, q1 = qa[i][1][r] * dn;
            float q2 = qa[i][2][r] * dn, q3 = qa[i][3][r] * dn;
            float mq = fmaxf(fmaxf(q0, q1), fmaxf(q2, q3));
#pragma unroll
            for (int o = 1; o < 16; o <<= 1) mq = fmaxf(mq, __shfl_xor(mq, o, 64));
            const float dg = sdq[row];
            const size_t ob = (size_t)t0 * 1024 + (size_t)row * 64 + lm;
            qf[ob]      = f2bf(0.125f * (expf(q0 - dg - mq) + 1e-6f));
            qf[ob + 16] = f2bf(0.125f * (expf(q1 - dg - mq) + 1e-6f));
            qf[ob + 32] = f2bf(0.125f * (expf(q2 - dg - mq) + 1e-6f));
            qf[ob + 48] = f2bf(0.125f * (expf(q3 - dg - mq) + 1e-6f));
#pragma unroll
            for (int ni = 0; ni < 4; ++ni) {
                float kd = ka[i][ni][r] * dn;
                kdash[ob + ni * 16] = f2bf(kd);
                kmax = fmaxf(kmax, kd);
            }
        }
    }
    kmax = wave_max(kmax);
    if (l == 0) swm[w] = kmax;
    __syncthreads();
    if (tid < 128) diagk[t0 * 16 + tid] = sdk[tid];
    if (tid == 0) bmax[blockIdx.x] = fmaxf(fmaxf(swm[0], swm[1]), fmaxf(swm[2], swm[3]));
}

__global__ __launch_bounds__(256) void max_reduce(const float* bm, float* mx) {
    const int tid = threadIdx.x;
    float m = -3.0e38f;
    for (int i = tid; i < 2048; i += 256) m = fmaxf(m, bm[i]);
    m = wave_max(m);
    __shared__ float s[4];
    if ((tid & 63) == 0) s[tid >> 6] = m;
    __syncthreads();
    if (tid == 0) mx[0] = fmaxf(fmaxf(s[0], s[1]), fmaxf(s[2], s[3]));
}

// ---------- fused kf + kv/ksum via MFMA (kdash bf16 in) ----------
__global__ __launch_bounds__(256, 2) void kv_fused(
    const unsigned short* __restrict__ kdash, const float* __restrict__ diagk,
    const float* __restrict__ mx, const unsigned short* __restrict__ vT,
    float* kv, float* ksum)
{
    __shared__ __align__(16) unsigned short sKF[64 * 72];
    __shared__ __align__(16) unsigned short sV[64 * 72];
    __shared__ float sDiag[1024];
    const int tid = threadIdx.x, w = tid >> 6, l = tid & 63;
    const int bh = blockIdx.x, b = bh >> 4, h = bh & 15;
    const int n0 = blockIdx.y * 1024;
    const int lm = l & 15, lq = l >> 4;
    const float mxv = mx[0];

    for (int i = tid; i < 1024; i += 256)
        sDiag[i] = diagk[(size_t)(b * 4096 + n0 + i) * 16 + h] + mxv;

    s16x8 onesf;
    {
        short ov = (lm == 0) ? (short)0x3F80 : (short)0;
#pragma unroll
        for (int j = 0; j < 8; ++j) onesf[j] = ov;
    }
    f32x4 acc[4] = {};
    f32x4 accS = {};
    __syncthreads();

    for (int c0 = 0; c0 < 1024; c0 += 64) {
        __syncthreads();
        {
            const int n = c0 + l;
            const size_t krow = ((size_t)(b * 4096 + n0 + n)) * 1024 + h * 64 + w * 16;
            const uint4* kp = (const uint4*)(kdash + krow);
            uint4 a0 = kp[0], a1 = kp[1];
            unsigned int words[8] = {a0.x, a0.y, a0.z, a0.w, a1.x, a1.y, a1.z, a1.w};
            const float dg = sDiag[n];
            unsigned short* dst = sKF + (w * 16) * 72 + l;
#pragma unroll
            for (int j = 0; j < 8; ++j) {
                float v0 = bf2f((unsigned short)(words[j] & 0xffffu));
                float v1 = bf2f((unsigned short)(words[j] >> 16));
                dst[(2 * j) * 72]     = f2bf(0.125f * (expf(v0 - dg) + 1e-6f));
                dst[(2 * j + 1) * 72] = f2bf(0.125f * (expf(v1 - dg) + 1e-6f));
            }
        }
        {
            const int d = tid >> 2, nq = tid & 3;
            const uint4* vp = (const uint4*)(vT + ((size_t)bh * 64 + d) * 4096 + n0 + c0 + nq * 16);
            uint4 v0 = vp[0], v1 = vp[1];
            uint4* ldst = (uint4*)(sV + d * 72 + nq * 16);
            ldst[0] = v0; ldst[1] = v1;
        }
        __syncthreads();
#pragma unroll
        for (int ks = 0; ks < 2; ++ks) {
            s16x8 a = *(const s16x8*)(sKF + (w * 16 + lm) * 72 + ks * 32 + lq * 8);
            accS = __builtin_amdgcn_mfma_f32_16x16x32_bf16(a, onesf, accS, 0, 0, 0);
#pragma unroll
            for (int ni = 0; ni < 4; ++ni) {
                s16x8 bf = *(const s16x8*)(sV + (ni * 16 + lm) * 72 + ks * 32 + lq * 8);
                acc[ni] = __builtin_amdgcn_mfma_f32_16x16x32_bf16(a, bf, acc[ni], 0, 0, 0);
            }
        }
    }

    const size_t kvbase = (size_t)bh * 4096;
#pragma unroll
    for (int ni = 0; ni < 4; ++ni)
#pragma unroll
        for (int r = 0; r < 4; ++r)
            atomicAdd(kv + kvbase + (size_t)(w * 16 + lq * 4 + r) * 64 + ni * 16 + lm, acc[ni][r]);
    if (lm == 0)
#pragma unroll
        for (int r = 0; r < 4; ++r)
            atomicAdd(ksum + bh * 64 + w * 16 + lq * 4 + r, accS[r]);
}

// ---------- attention combine via MFMA, den folded as output column 64 ----------
__global__ __launch_bounds__(256, 2) void attn_mfma(const unsigned short* __restrict__ qf,
                                                    const float* __restrict__ kv,
                                                    const float* __restrict__ ksum,
                                                    unsigned short* __restrict__ attn) {
    __shared__ __align__(16) unsigned short sA[8192];  // [2 ks][128 rows][32 m]
    __shared__ __align__(16) unsigned short sB[5120];  // [2 ks][80 cols][32 m]; col64=ksum
    const int tid = threadIdx.x, w = tid >> 6, l = tid & 63;
    const int bh = blockIdx.x, b = bh >> 4, h = bh & 15;
    const int n0 = blockIdx.y * 128;
    const int lm = l & 15, lq = l >> 4;

#pragma unroll
    for (int j = 0; j < 4; ++j) {
        const int r0 = w * 32 + (j & 1) * 16, ks = j >> 1;
        const size_t g = (size_t)(b * 4096 + n0 + r0 + (l >> 2)) * 1024 + h * 64 + ks * 32 + (l & 3) * 8;
        async_load16(qf + g, sA + ks * 4096 + r0 * 32);
    }
    for (int i = tid; i < 5120; i += 256) sB[i] = 0;
    __syncthreads();
    for (int i = tid; i < 4096; i += 256) {
        int m = i >> 6, d = i & 63;
        sB[(m >> 5) * 2560 + d * 32 + (m & 31)] = f2bf(kv[(size_t)bh * 4096 + i]);
    }
    if (tid < 64) {
        int m = tid;
        sB[(m >> 5) * 2560 + 64 * 32 + (m & 31)] = f2bf(ksum[bh * 64 + m]);
    }
    __syncthreads();

    s16x8 bf2r[2][5];
#pragma unroll
    for (int ks = 0; ks < 2; ++ks)
#pragma unroll
        for (int ni = 0; ni < 5; ++ni)
            bf2r[ks][ni] = *(const s16x8*)(sB + ks * 2560 + (ni * 16 + lm) * 32 + lq * 8);
    f32x4 acc[2][5] = {};
#pragma unroll
    for (int i = 0; i < 2; ++i) {
        const int rowt = (w * 2 + i) * 16 + lm;
#pragma unroll
        for (int ks = 0; ks < 2; ++ks) {
            s16x8 a = *(const s16x8*)(sA + ks * 4096 + rowt * 32 + lq * 8);
#pragma unroll
            for (int ni = 0; ni < 5; ++ni)
                acc[i][ni] = __builtin_amdgcn_mfma_f32_16x16x32_bf16(a, bf2r[ks][ni], acc[i][ni], 0, 0, 0);
        }
    }
#pragma unroll
    for (int i = 0; i < 2; ++i) {
#pragma unroll
        for (int r = 0; r < 4; ++r) {
            const int row = (w * 2 + i) * 16 + lq * 4 + r;
            float den = __shfl(acc[i][4][r], l & 48, 64);
            float rd = 1.f / den;
            const size_t ob = (size_t)(b * 4096 + n0 + row) * 1024 + h * 64 + lm;
            attn[ob]      = f2bf(acc[i][0][r] * rd);
            attn[ob + 16] = f2bf(acc[i][1][r] * rd);
            attn[ob + 32] = f2bf(acc[i][2][r] * rd);
            attn[ob + 48] = f2bf(acc[i][3][r] * rd);
        }
    }
}

// ---------- LayerNorm (D=1024), optional bf16 input ----------
__device__ __forceinline__ float block_sum256(float v, float* sbuf, int tid) {
    v = wave_sum(v);
    __syncthreads();
    if ((tid & 63) == 0) sbuf[tid >> 6] = v;
    __syncthreads();
    return sbuf[0] + sbuf[1] + sbuf[2] + sbuf[3];
}

template <int RBF16, int WF32, int WBF16>
__global__ __launch_bounds__(256) void ln_kernel(const float* src, const unsigned short* srcb,
                                                 const float* g, const float* b,
                                                 float* dstf, unsigned short* dstb) {
    __shared__ float sbuf[4];
    const int t = blockIdx.x, tid = threadIdx.x;
    float4 v;
    if (RBF16) {
        ushort4 u = ((const ushort4*)(srcb + (size_t)t * 1024))[tid];
        v.x = bf2f(u.x); v.y = bf2f(u.y); v.z = bf2f(u.z); v.w = bf2f(u.w);
    } else {
        v = ((const float4*)(src + (size_t)t * 1024))[tid];
    }
    float mu = block_sum256(v.x + v.y + v.z + v.w, sbuf, tid) * (1.f / 1024.f);
    float dx = v.x - mu, dy = v.y - mu, dz = v.z - mu, dw = v.w - mu;
    float var = block_sum256(dx * dx + dy * dy + dz * dz + dw * dw, sbuf, tid) * (1.f / 1024.f);
    float r = rsqrtf(var + 1e-6f);
    float4 gv = ((const float4*)g)[tid];
    float4 bv = ((const float4*)b)[tid];
    float4 o;
    o.x = dx * r * gv.x + bv.x; o.y = dy * r * gv.y + bv.y;
    o.z = dz * r * gv.z + bv.z; o.w = dw * r * gv.w + bv.w;
    if (WF32) ((float4*)(dstf + (size_t)t * 1024))[tid] = o;
    if (WBF16) {
        ushort4 u; u.x = f2bf(o.x); u.y = f2bf(o.y); u.z = f2bf(o.z); u.w = f2bf(o.w);
        ((ushort4*)(dstb + (size_t)t * 1024))[tid] = u;
    }
}

// ---------- launcher ----------
extern "C" void kernel_launch(void* const* d_in, const int* in_sizes, int n_in,
                              void* d_out, int out_size, void* d_ws, size_t ws_size,
                              hipStream_t stream) {
    (void)in_sizes; (void)n_in; (void)out_size; (void)ws_size;
    const float* x    = (const float*)d_in[0];
    const float* Wq   = (const float*)d_in[1];
    const float* Wk   = (const float*)d_in[2];
    const float* Wv   = (const float*)d_in[3];
    const float* Wo   = (const float*)d_in[4];
    const float* proj = (const float*)d_in[5];
    const float* W1   = (const float*)d_in[6];
    const float* b1   = (const float*)d_in[7];
    const float* W2   = (const float*)d_in[8];
    const float* b2   = (const float*)d_in[9];
    const float* g1   = (const float*)d_in[10];
    const float* lb1  = (const float*)d_in[11];
    const float* g2   = (const float*)d_in[12];
    const float* lb2  = (const float*)d_in[13];

    char* ws = (char*)d_ws;
    size_t off = 0;
    auto alloc = [&](size_t bytes) { char* p = ws + off; off += (bytes + 255) & ~(size_t)255; return p; };
    unsigned short* WqkvT = (unsigned short*)alloc((size_t)3072 * 1024 * 2);
    unsigned short* WoT   = (unsigned short*)alloc((size_t)1024 * 1024 * 2);
    unsigned short* W1T   = (unsigned short*)alloc((size_t)4096 * 1024 * 2);
    unsigned short* W2T   = (unsigned short*)alloc((size_t)1024 * 4096 * 2);
    unsigned short* xb    = (unsigned short*)alloc((size_t)16384 * 1024 * 2);  // later: attn
    unsigned short* qkvb  = (unsigned short*)alloc((size_t)16384 * 3072 * 2);  // later: out1b + h(lo)
    unsigned short* qf    = (unsigned short*)alloc((size_t)16384 * 1024 * 2);  // later: h(mid)
    unsigned short* vT    = (unsigned short*)alloc((size_t)16384 * 1024 * 2);  // later: h(hi)
    float* kv    = (float*)alloc((size_t)64 * 64 * 64 * 4);
    float* ksum  = (float*)alloc((size_t)64 * 64 * 4);
    float* diagk = (float*)alloc((size_t)16384 * 16 * 4);
    float* bmax  = (float*)alloc((size_t)16384 * 4);
    float* mx    = (float*)alloc(256);

    unsigned short* attnb = xb;
    unsigned short* out1b = qkvb;                                   // 32 MB
    unsigned short* h     = qkvb + (size_t)16384 * 1024;            // 128 MB (qkvb hi + qf + vT)
    // d_out (67MB f32) doubles as scratch, sequentially reused:
    unsigned short* kdash  = (unsigned short*)d_out;   // bf16 32MB (feat -> kv_fused)
    unsigned short* preLNb = (unsigned short*)d_out;   // bf16 32MB (Wo -> ln1), after kv_fused
    float* preLN = (float*)d_out;                      // f32 67MB (FFN2 -> ln2)

    transpose_all<<<12288, dim3(32, 8), 0, stream>>>(Wq, Wk, Wv, Wo, W1, W2,
                                                     WqkvT, WoT, W1T, W2T);
    cvt_bf16<<<16384, 256, 0, stream>>>((const float4*)x, (ushort4*)xb);

    // QKV: [16384,1024] x [1024,3072]; Q,K -> qkvb (bf16), V -> vT (transposed)
    gemm_bt<EP_QKV><<<dim3(24, 128), 256, 0, stream>>>(xb, 1024, WqkvT, 1024, 1024, 3072,
                                                       nullptr, qkvb, nullptr, nullptr, nullptr, vT);
    feat_mfma<<<2048, 256, 0, stream>>>(qkvb, proj, qf, kdash, diagk, bmax);
    max_reduce<<<1, 256, 0, stream>>>(bmax, mx);
    hipMemsetAsync(kv, 0, (size_t)64 * 64 * 64 * 4 + (size_t)64 * 64 * 4, stream);
    kv_fused<<<dim3(64, 4), 256, 0, stream>>>(kdash, diagk, mx, vT, kv, ksum);
    attn_mfma<<<dim3(64, 32), 256, 0, stream>>>(qf, kv, ksum, attnb);
    // attn @ Wo + x -> preLN1 (bf16, in d_out)
    gemm_bt<EP_ADDF32B><<<dim3(8, 128), 256, 0, stream>>>(attnb, 1024, WoT, 1024, 1024, 1024,
                                                          nullptr, preLNb, nullptr, x, nullptr, nullptr);
    ln_kernel<1, 0, 1><<<16384, 256, 0, stream>>>(nullptr, preLNb, g1, lb1, nullptr, out1b);
    // FFN full-DFF: h = elu(out1b @ W1 + b1)  [16384,4096]
    gemm_bt<EP_BIAS_ELU_BF16><<<dim3(32, 128), 256, 0, stream>>>(out1b, 1024, W1T, 1024, 1024, 4096,
                                                                 nullptr, h, b1, nullptr, nullptr, nullptr);
    // preLN2 = h @ W2 + b2 + out1  (K=4096, f32 out)
    gemm_bt<EP_BIAS_ADDBF16><<<dim3(8, 128), 256, 0, stream>>>(h, 4096, W2T, 4096, 4096, 1024,
                                                               preLN, nullptr, b2, nullptr, out1b, nullptr);
    ln_kernel<0, 1, 0><<<16384, 256, 0, stream>>>(preLN, nullptr, g2, lb2, (float*)d_out, nullptr);
}